// Round 8
// baseline (1749.409 us; speedup 1.0000x reference)
//
#include <hip/hip_runtime.h>
#include <hip/hip_bf16.h>
#include <hip/hip_fp16.h>

typedef __attribute__((ext_vector_type(8))) short short8;
typedef __attribute__((ext_vector_type(4))) float f32x4;

__device__ __forceinline__ unsigned short dev_f2bf(float f) {
  __hip_bfloat16 b = __float2bfloat16(f);
  union { __hip_bfloat16 b; unsigned short u; } c; c.b = b; return c.u;
}
__device__ __forceinline__ float dev_bf2f(unsigned short u) {
  union { unsigned int i; float f; } c; c.i = ((unsigned int)u) << 16; return c.f;
}
__device__ __forceinline__ unsigned short dev_f2h(float f) {
  __half h = __float2half(f);
  union { __half h; unsigned short u; } c; c.h = h; return c.u;
}
__device__ __forceinline__ float dev_h2f(unsigned short u) {
  union { unsigned short u; __half h; } c; c.u = u; return __half2float(c.h);
}

// async global->LDS, 16B per lane; dest = lds_base(wave-uniform) + lane*16
__device__ __forceinline__ void gload_lds16(const unsigned short* g, unsigned short* l) {
  __builtin_amdgcn_global_load_lds(
      (const __attribute__((address_space(1))) void*)(const void*)g,
      (__attribute__((address_space(3))) void*)(void*)l, 16, 0, 0);
}

struct GemmP {
  const unsigned short* A;   // bf16 bits
  const unsigned short* B;   // bf16 bits
  void* C;
  const float* biasN;        // bias by output col, may be null
  const float* biasM;        // bias by output row, may be null
  long long aHi, aLo, bHi, bLo, cHi, cLo;  // per-z base: (z>>4)*Hi + (z&15)*Lo
  int K;
  int sAm;                   // A row stride (k stride == 1)
  int sBn;                   // B row stride (k stride == 1)
  int sCm, sCn;
  float scale;
  int relu;
  int cdtype;                // 0=bf16, 1=f32, 2=f16, 3=f32 +=
};

#define VM8() asm volatile("s_waitcnt vmcnt(8)" ::: "memory")
#define VM4() asm volatile("s_waitcnt vmcnt(4)" ::: "memory")
#define VM0() asm volatile("s_waitcnt vmcnt(0)" ::: "memory")
#define SB0() __builtin_amdgcn_sched_barrier(0)

// ---------------------------------------------------------------------------
// Big-GEMM: 256x256 tile, 512 threads (8 waves 2Mx4N), BK=64 in two k-halves.
// LDS [2 dbuf][A-kh0|A-kh1|B-kh0|B-kh1][256x32 shorts] = 128 KiB.
// 2 phases per K-tile (one per k-half): 12 ds_read_b128 (pa[8]+pb[4], each
// frag read ONCE per K-tile -> 24 reads/wave/K-tile) + 2 stage units +
// barrier + setprio'd 32 MFMA + counted vmcnt (VM8 steady, VM4/VM0 tail;
// 12 outstanding at every phase-end, VM8 completes exactly the 4 needed
// next) + barrier. XOR swizzle: LDS[r][c16] = G[r][c16 ^ ((r>>1)&3)].
// Requires: M%256==0, N%256==0, K%64==0, k-contiguous A/B, C row-major sCn==1.
// ---------------------------------------------------------------------------
__global__ __launch_bounds__(512, 2) void gemm8(GemmP p) {
  __shared__ __align__(16) unsigned short lds[2][4][8192];  // 128 KiB

  const int tid = threadIdx.x;
  const int lane = tid & 63;
  const int wid = tid >> 6;       // 0..7
  const int wm = wid >> 2;        // 0..1
  const int wn = wid & 3;         // 0..3
  const int rl = lane & 15;
  const int kq = lane >> 4;       // 0..3 (8-short k-chunk within K-half)

  // XCD-aware bijective block swizzle (only when nwg % 8 == 0)
  int id = blockIdx.y * gridDim.x + blockIdx.x;
  const int nwg = gridDim.x * gridDim.y;
  if ((nwg & 7) == 0) id = (id & 7) * (nwg >> 3) + (id >> 3);
  const long long m0 = (long long)(id % gridDim.x) * 256;
  const long long n0 = (long long)(id / gridDim.x) * 256;

  const int sr0 = tid >> 2;      // 0..127
  const int sc = tid & 3;

  f32x4 acc[8][4];
#pragma unroll
  for (int i = 0; i < 8; i++)
#pragma unroll
    for (int j = 0; j < 4; j++)
      acc[i][j] = f32x4{0.f, 0.f, 0.f, 0.f};

  const int nt = p.K >> 6;

  // reg: 0=A-kh0, 1=A-kh1, 2=B-kh0, 3=B-kh1 ; one unit = 2 gloads/thread
  auto unit = [&](int buf, int reg, int t) {
    const bool isB = reg >= 2;
    const unsigned short* src = isB ? p.B : p.A;
    const long long r0 = isB ? n0 : m0;
    const long long stride = isB ? p.sBn : p.sAm;
    const long long k0 = (long long)t * 64 + (reg & 1) * 32;
#pragma unroll
    for (int j = 0; j < 2; j++) {
      const int r = j * 128 + sr0;
      gload_lds16(src + (r0 + r) * stride + k0 + ((sc ^ ((r >> 1) & 3)) << 3),
                  &lds[buf][reg][(j * 512 + wid * 64) * 8]);
    }
  };

#define PHASE(CUR, KS, ISSUE_STMT, WAIT_STMT)                                  \
  do {                                                                         \
    short8 pa[8], pb[4];                                                       \
    _Pragma("unroll") for (int i = 0; i < 8; i++) {                            \
      const int ra = wm * 128 + i * 16 + rl;                                   \
      pa[i] = *(const short8*)&lds[CUR][KS][ra * 32 + ((kq ^ ((ra >> 1) & 3)) << 3)]; \
    }                                                                          \
    _Pragma("unroll") for (int j = 0; j < 4; j++) {                            \
      const int rb = wn * 64 + j * 16 + rl;                                    \
      pb[j] = *(const short8*)&lds[CUR][2 + (KS)][rb * 32 + ((kq ^ ((rb >> 1) & 3)) << 3)]; \
    }                                                                          \
    ISSUE_STMT;                                                                \
    SB0();                                                                     \
    __builtin_amdgcn_s_barrier();                                              \
    SB0();                                                                     \
    __builtin_amdgcn_s_setprio(1);                                             \
    _Pragma("unroll") for (int i = 0; i < 8; i++)                              \
      _Pragma("unroll") for (int j = 0; j < 4; j++)                            \
        acc[i][j] = __builtin_amdgcn_mfma_f32_16x16x32_bf16(                   \
            pa[i], pb[j], acc[i][j], 0, 0, 0);                                 \
    __builtin_amdgcn_s_setprio(0);                                             \
    SB0();                                                                     \
    WAIT_STMT;                                                                 \
    __builtin_amdgcn_s_barrier();                                              \
    SB0();                                                                     \
  } while (0)

  // prologue: A0(0) B0(0) A1(0) B1(0) A0(1) B0(1)
  unit(0, 0, 0); unit(0, 2, 0); unit(0, 1, 0); unit(0, 3, 0);
  if (nt > 1) { unit(1, 0, 1); unit(1, 2, 1); VM8(); }
  else        { VM4(); }
  SB0();
  __builtin_amdgcn_s_barrier();
  SB0();

  for (int t = 0; t < nt; t++) {
    const int cur = t & 1;
    PHASE(cur, 0,
          { if (t + 1 < nt) { unit(cur ^ 1, 1, t + 1); unit(cur ^ 1, 3, t + 1); } },
          { if (t + 1 < nt) { VM8(); } else { VM0(); } });
    PHASE(cur, 1,
          { if (t + 2 < nt) { unit(cur, 0, t + 2); unit(cur, 2, t + 2); } },
          { if (t + 2 < nt) { VM8(); } else if (t + 1 < nt) { VM4(); } });
  }
#undef PHASE

#pragma unroll
  for (int i = 0; i < 8; i++) {
#pragma unroll
    for (int j = 0; j < 4; j++) {
      const int col = (int)n0 + wn * 64 + j * 16 + rl;
      float bn = p.biasN ? p.biasN[col] : 0.f;
#pragma unroll
      for (int r = 0; r < 4; r++) {
        const long long row = m0 + wm * 128 + i * 16 + ((lane >> 4) << 2) + r;
        float v = acc[i][j][r] * p.scale + bn;
        if (p.relu) v = fmaxf(v, 0.f);
        const long long addr = row * p.sCm + col;
        if (p.cdtype == 0)      ((unsigned short*)p.C)[addr] = dev_f2bf(v);
        else if (p.cdtype == 3) ((float*)p.C)[addr] += v;
        else                    ((float*)p.C)[addr] = v;
      }
    }
  }
}

// General NT GEMM (small/batched shapes): C[z,m,n] = scale*sum_k A[m,k]*B[n,k]
template<int BM, int BN, int WM, int WN>
__global__ __launch_bounds__(256, 2) void gemm_nt(GemmP p) {
  constexpr int BK = 64;
  constexpr int TM = BM / WM, TN = BN / WN;
  constexpr int FM = TM / 16, FN = TN / 16;
  __shared__ __align__(16) unsigned short As[BM * BK];
  __shared__ __align__(16) unsigned short Bs[BN * BK];

  const int tid = threadIdx.x;
  const int lane = tid & 63;
  const int wid = tid >> 6;
  const int wm = wid / WN, wn = wid % WN;
  const int m0 = blockIdx.x * BM;
  const int n0 = blockIdx.y * BN;
  const int z = blockIdx.z;
  const int zq = z >> 4, zr = z & 15;
  const unsigned short* Ag = p.A + (long long)zq * p.aHi + (long long)zr * p.aLo;
  const unsigned short* Bg = p.B + (long long)zq * p.bHi + (long long)zr * p.bLo;

  const int srow = tid >> 3;                      // 0..31
  const int scol = ((tid & 7) ^ (srow & 7)) * 8;  // swizzled 16B column
  constexpr int AC = BM / 32, BC = BN / 32;

  f32x4 acc[FM][FN];
#pragma unroll
  for (int i = 0; i < FM; i++)
#pragma unroll
    for (int j = 0; j < FN; j++)
      acc[i][j] = f32x4{0.f, 0.f, 0.f, 0.f};

  for (int k0 = 0; k0 < p.K; k0 += BK) {
#pragma unroll
    for (int i = 0; i < AC; i++)
      gload_lds16(Ag + (long long)(m0 + i * 32 + srow) * p.sAm + (k0 + scol),
                  &As[i * 2048 + wid * 512]);
#pragma unroll
    for (int i = 0; i < BC; i++)
      gload_lds16(Bg + (long long)(n0 + i * 32 + srow) * p.sBn + (k0 + scol),
                  &Bs[i * 2048 + wid * 512]);
    __syncthreads();
#pragma unroll
    for (int ks = 0; ks < 2; ks++) {
      const int c16 = ks * 4 + (lane >> 4);
      short8 a[FM], b[FN];
#pragma unroll
      for (int i = 0; i < FM; i++) {
        const int row = wm * TM + i * 16 + (lane & 15);
        a[i] = *(const short8*)&As[row * 64 + ((c16 ^ (row & 7)) << 3)];
      }
#pragma unroll
      for (int j = 0; j < FN; j++) {
        const int row = wn * TN + j * 16 + (lane & 15);
        b[j] = *(const short8*)&Bs[row * 64 + ((c16 ^ (row & 7)) << 3)];
      }
#pragma unroll
      for (int i = 0; i < FM; i++)
#pragma unroll
        for (int j = 0; j < FN; j++)
          acc[i][j] = __builtin_amdgcn_mfma_f32_16x16x32_bf16(a[i], b[j], acc[i][j], 0, 0, 0);
    }
    __syncthreads();
  }

  const long long zc_ = (long long)zq * p.cHi + (long long)zr * p.cLo;
#pragma unroll
  for (int i = 0; i < FM; i++) {
#pragma unroll
    for (int j = 0; j < FN; j++) {
      const int col = n0 + wn * TN + j * 16 + (lane & 15);
      float bn = p.biasN ? p.biasN[col] : 0.f;
#pragma unroll
      for (int r = 0; r < 4; r++) {
        const int row = m0 + wm * TM + i * 16 + ((lane >> 4) << 2) + r;
        float v = acc[i][j][r] * p.scale + bn;
        if (p.biasM) v += p.biasM[row];
        if (p.relu) v = fmaxf(v, 0.f);
        const long long addr = zc_ + (long long)row * p.sCm + (long long)col * p.sCn;
        if (p.cdtype == 0)      ((unsigned short*)p.C)[addr] = dev_f2bf(v);
        else if (p.cdtype == 1) ((float*)p.C)[addr] = v;
        else if (p.cdtype == 2) ((unsigned short*)p.C)[addr] = dev_f2h(v);
        else                    ((float*)p.C)[addr] += v;
      }
    }
  }
}

// 64x64 tiled transpose: in [b][4096][1024] -> out [b][1024][4096] (bf16)
__global__ __launch_bounds__(256) void transpose_kernel(const unsigned short* __restrict__ in,
                                                        unsigned short* __restrict__ out) {
  __shared__ unsigned short t[64][72];
  const int b = blockIdx.z;
  const int n0 = blockIdx.x * 64, c0 = blockIdx.y * 64;
  const int r = threadIdx.x >> 2;          // 0..63
  const int cc = (threadIdx.x & 3) * 16;   // 0,16,32,48
  const unsigned short* ip = in + (size_t)b * 4194304 + (size_t)n0 * 1024 + c0;
  *(short8*)&t[r][cc]     = *(const short8*)(ip + (size_t)r * 1024 + cc);
  *(short8*)&t[r][cc + 8] = *(const short8*)(ip + (size_t)r * 1024 + cc + 8);
  __syncthreads();
  unsigned short* op = out + (size_t)b * 4194304 + (size_t)c0 * 4096 + n0;
  short8 w0, w1;
#pragma unroll
  for (int j = 0; j < 8; j++) {
    w0[j] = (short)t[cc + j][r];
    w1[j] = (short)t[cc + 8 + j][r];
  }
  *(short8*)(op + (size_t)r * 4096 + cc)     = w0;
  *(short8*)(op + (size_t)r * 4096 + cc + 8) = w1;
}

// f32 -> bf16 (optionally also copy raw f32), x4 vectorized, grid-stride
__global__ void cvt_kernel(const float* __restrict__ src, unsigned short* __restrict__ dst,
                           float* __restrict__ dstf, long long n4) {
  long long i = (long long)blockIdx.x * blockDim.x + threadIdx.x;
  const long long stride = (long long)gridDim.x * blockDim.x;
  for (; i < n4; i += stride) {
    float4 v = ((const float4*)src)[i];
    ushort4 u;
    u.x = dev_f2bf(v.x); u.y = dev_f2bf(v.y); u.z = dev_f2bf(v.z); u.w = dev_f2bf(v.w);
    ((ushort4*)dst)[i] = u;
    if (dstf) ((float4*)dstf)[i] = v;
  }
}

// rows of 256: f16 scores in, bf16 probs out, in place; one wave per row
__global__ __launch_bounds__(256) void softmax_kernel(unsigned short* __restrict__ S) {
  const long long row = (long long)blockIdx.x * 4 + (threadIdx.x >> 6);
  const int lane = threadIdx.x & 63;
  unsigned short* rp = S + row * 256;
  ushort4 u = *(const ushort4*)(rp + lane * 4);
  float x0 = dev_h2f(u.x), x1 = dev_h2f(u.y), x2 = dev_h2f(u.z), x3 = dev_h2f(u.w);
  float m = fmaxf(fmaxf(x0, x1), fmaxf(x2, x3));
#pragma unroll
  for (int off = 32; off > 0; off >>= 1) m = fmaxf(m, __shfl_xor(m, off));
  float e0 = __expf(x0 - m), e1 = __expf(x1 - m), e2 = __expf(x2 - m), e3 = __expf(x3 - m);
  float s = e0 + e1 + e2 + e3;
#pragma unroll
  for (int off = 32; off > 0; off >>= 1) s += __shfl_xor(s, off);
  const float inv = 1.f / s;
  ushort4 o;
  o.x = dev_f2bf(e0 * inv); o.y = dev_f2bf(e1 * inv);
  o.z = dev_f2bf(e2 * inv); o.w = dev_f2bf(e3 * inv);
  *(ushort4*)(rp + lane * 4) = o;
}

// LN over rows of 1024 of xf (f32, holds x+y). Writes LN to xf and bf16 to xd (if xd).
__global__ __launch_bounds__(256) void add_ln_kernel(float* __restrict__ xf,
    unsigned short* __restrict__ xd,
    const float* __restrict__ g, const float* __restrict__ b) {
  const long long row = blockIdx.x;
  const int tid = threadIdx.x;
  float4 t = ((const float4*)(xf + row * 1024))[tid];
  float s = t.x + t.y + t.z + t.w;
  float ss = t.x * t.x + t.y * t.y + t.z * t.z + t.w * t.w;
#pragma unroll
  for (int off = 32; off > 0; off >>= 1) { s += __shfl_xor(s, off); ss += __shfl_xor(ss, off); }
  __shared__ float sm[8];
  const int wid = tid >> 6, lane = tid & 63;
  if (lane == 0) { sm[wid] = s; sm[4 + wid] = ss; }
  __syncthreads();
  s = sm[0] + sm[1] + sm[2] + sm[3];
  ss = sm[4] + sm[5] + sm[6] + sm[7];
  const float mean = s * (1.f / 1024.f);
  const float var = ss * (1.f / 1024.f) - mean * mean;
  const float rs = rsqrtf(var + 1e-5f);
  float4 gv = ((const float4*)g)[tid];
  float4 bv = ((const float4*)b)[tid];
  float4 o = {(t.x - mean) * rs * gv.x + bv.x, (t.y - mean) * rs * gv.y + bv.y,
              (t.z - mean) * rs * gv.z + bv.z, (t.w - mean) * rs * gv.w + bv.w};
  ((float4*)(xf + row * 1024))[tid] = o;
  if (xd) {
    ushort4 ob;
    ob.x = dev_f2bf(o.x); ob.y = dev_f2bf(o.y); ob.z = dev_f2bf(o.z); ob.w = dev_f2bf(o.w);
    ((ushort4*)(xd + row * 1024))[tid] = ob;
  }
}

// canary: unambiguous "workspace too small" signal (absmax ~ 100+max|ref|)
__global__ void fill_canary_kernel(float* p, long long n) {
  long long i = (long long)blockIdx.x * blockDim.x + threadIdx.x;
  const long long stride = (long long)gridDim.x * blockDim.x;
  for (; i < n; i += stride) p[i] = 100.0f;
}

extern "C" void kernel_launch(void* const* d_in, const int* in_sizes, int n_in,
                              void* d_out, int out_size, void* d_ws, size_t ws_size,
                              hipStream_t stream) {
  const float* x_in  = (const float*)d_in[0];
  const float* E_w   = (const float*)d_in[1];
  const float* E_b   = (const float*)d_in[2];
  const float* Wq    = (const float*)d_in[3];
  const float* Wk    = (const float*)d_in[4];
  const float* Wv    = (const float*)d_in[5];
  const float* wo_w  = (const float*)d_in[6];
  const float* wo_b  = (const float*)d_in[7];
  const float* ln1_g = (const float*)d_in[8];
  const float* ln1_b = (const float*)d_in[9];
  const float* ff_w1 = (const float*)d_in[10];
  const float* ff_b1 = (const float*)d_in[11];
  const float* ff_w2 = (const float*)d_in[12];
  const float* ff_b2 = (const float*)d_in[13];
  const float* ln2_g = (const float*)d_in[14];
  const float* ln2_b = (const float*)d_in[15];

  float* xf = (float*)d_out;   // f32 residual master lives in d_out

  char* ws = (char*)d_ws;
  size_t off = 0;
  auto alloc = [&](size_t bytes) -> char* {
    char* p = ws + off;
    off = (off + bytes + 255) & ~(size_t)255;
    return p;
  };
  unsigned short* E16 = (unsigned short*)alloc(1048576ULL * 2);  // E_w bf16 [256,4096]
  unsigned short* WqL = (unsigned short*)alloc(1048576ULL * 2);  // per-layer slices
  unsigned short* WkL = (unsigned short*)alloc(1048576ULL * 2);
  unsigned short* WvL = (unsigned short*)alloc(1048576ULL * 2);
  unsigned short* WoL = (unsigned short*)alloc(1048576ULL * 2);
  unsigned short* F1L = (unsigned short*)alloc(4194304ULL * 2);
  unsigned short* F2L = (unsigned short*)alloc(4194304ULL * 2);
  unsigned short* xE  = (unsigned short*)alloc(1048576ULL * 2);  // [b][256][1024]
  unsigned short* EK  = (unsigned short*)alloc(1048576ULL * 2);  // [z][256][64]
  unsigned short* EVt = (unsigned short*)alloc(1048576ULL * 2);  // [z][64][256]
  unsigned short* xd  = (unsigned short*)alloc(16777216ULL * 2); // bf16 working x
  unsigned short* xT  = (unsigned short*)alloc(16777216ULL * 2); // x^T [b][1024][4096]; later Q/cat
  unsigned short* Qb4 = xT;   // alias: xT dead once pe is done; Q/cat [16384][1024]

  size_t rem = (ws_size > off) ? ws_size - off : 0;
  size_t Rbytes = rem > 512 ? rem - 512 : 0;
  if (Rbytes > 134217728ULL) Rbytes = 134217728ULL;
  int zc = 64;     // heads-chunk over z=0..63 (S chunk = zc * 2 MiB)
  while (zc > 1 && (size_t)zc * 2097152ULL > Rbytes) zc >>= 1;
  int rowc = 16384;
  while (rowc > 256 && (size_t)rowc * 8192ULL > Rbytes) rowc >>= 1;
  if ((size_t)zc * 2097152ULL > Rbytes || (size_t)rowc * 8192ULL > Rbytes) {
    fill_canary_kernel<<<2048, 256, 0, stream>>>(xf, (long long)out_size);
    return;
  }
  char* R = alloc(Rbytes);

  auto cvt = [&](const float* s, unsigned short* d, float* df, long long n) {
    long long n4 = n / 4;
    int grid = (int)((n4 + 255) / 256);
    if (grid > 4096) grid = 4096;
    cvt_kernel<<<grid, 256, 0, stream>>>(s, d, df, n4);
  };

  cvt(x_in, xd, xf, 16777216);     // x: bf16 into ws, f32 master into d_out
  cvt(E_w, E16, nullptr, 1048576);

  for (int l = 0; l < 2; l++) {
    cvt(Wq + (size_t)l * 1048576, WqL, nullptr, 1048576);
    cvt(Wk + (size_t)l * 1048576, WkL, nullptr, 1048576);
    cvt(Wv + (size_t)l * 1048576, WvL, nullptr, 1048576);
    cvt(wo_w + (size_t)l * 1048576, WoL, nullptr, 1048576);
    cvt(ff_w1 + (size_t)l * 4194304, F1L, nullptr, 4194304);
    cvt(ff_w2 + (size_t)l * 4194304, F2L, nullptr, 4194304);

    // ---- xT[b][c][n] = x[b][n][c]
    transpose_kernel<<<dim3(64, 16, 4), 256, 0, stream>>>(xd, xT);

    // ---- xE[b][k][c] = sum_n E_w[k,n] * xT[b][c][n]   (pure NT, z = b)
    GemmP pe{};
    pe.A = E16; pe.sAm = 4096; pe.K = 4096;
    pe.B = xT; pe.sBn = 4096; pe.bLo = 4194304;
    pe.C = xE; pe.cLo = 262144; pe.sCm = 1024; pe.sCn = 1;
    pe.scale = 1.f; pe.cdtype = 0;
    gemm_nt<64,128,2,2><<<dim3(4, 8, 4), 256, 0, stream>>>(pe);

    // ---- EK[z][k][d] = xE[b] @ Wk[h]^T + E_b[k]   (z = b*16+h)
    GemmP pk{};
    pk.A = xE; pk.sAm = 1024; pk.K = 1024; pk.aHi = 262144; pk.aLo = 0;
    pk.B = WkL; pk.sBn = 1024; pk.bHi = 0; pk.bLo = 65536;
    pk.C = EK; pk.cHi = 262144; pk.cLo = 16384; pk.sCm = 64; pk.sCn = 1;
    pk.biasM = E_b; pk.scale = 1.f; pk.cdtype = 0;
    gemm_nt<64,64,2,2><<<dim3(4, 1, 64), 256, 0, stream>>>(pk);
    // ---- EVt[z][d][k] = (xE[b] @ Wv[h]^T + E_b[k])^T
    GemmP pv2 = pk;
    pv2.B = WvL; pv2.C = EVt; pv2.sCm = 1; pv2.sCn = 256;
    gemm_nt<64,64,2,2><<<dim3(4, 1, 64), 256, 0, stream>>>(pv2);

    // ---- Q (all batches) = x @ Wq^T : [16384,1024]   (overwrites xT region)
    GemmP pq{};
    pq.A = xd; pq.sAm = 1024; pq.K = 1024;
    pq.B = WqL; pq.sBn = 1024;
    pq.C = Qb4; pq.sCm = 1024; pq.sCn = 1;
    pq.scale = 1.f; pq.cdtype = 0;
    gemm8<<<dim3(64, 4, 1), 512, 0, stream>>>(pq);

    for (int z0 = 0; z0 < 64; z0 += zc) {
      const long long aOff = (long long)(z0 >> 4) * 4194304 + (long long)(z0 & 15) * 64;
      const long long eOff = (long long)z0 * 16384;
      // ---- S[zl][n][k] = 0.125 * Q[b, :, h*64:+64] @ EK[z]^T  (f16)
      GemmP ps{};
      ps.A = Qb4 + aOff; ps.aHi = 4194304; ps.aLo = 64; ps.sAm = 1024; ps.K = 64;
      ps.B = EK + eOff; ps.bHi = 262144; ps.bLo = 16384; ps.sBn = 64;
      ps.C = R; ps.cHi = 16777216; ps.cLo = 1048576; ps.sCm = 256; ps.sCn = 1;
      ps.scale = 0.125f; ps.cdtype = 2;
      gemm_nt<128,128,2,2><<<dim3(32, 2, zc), 256, 0, stream>>>(ps);

      softmax_kernel<<<zc * 1024, 256, 0, stream>>>((unsigned short*)R);

      // ---- attn = P @ EVt^T -> cat[b][n][h*64+d]  (cat aliases Qb4; per-z col slice)
      GemmP pp{};
      pp.A = (unsigned short*)R; pp.aHi = 16777216; pp.aLo = 1048576; pp.sAm = 256; pp.K = 256;
      pp.B = EVt + eOff; pp.bHi = 262144; pp.bLo = 16384; pp.sBn = 256;
      pp.C = Qb4 + aOff; pp.cHi = 4194304; pp.cLo = 64; pp.sCm = 1024; pp.sCn = 1;
      pp.scale = 1.f; pp.cdtype = 0;
      gemm_nt<128,64,4,1><<<dim3(32, 1, zc), 256, 0, stream>>>(pp);
    }

    // ---- xf += cat @ wo^T + wo_b   (f32 accumulate epilogue, all batches)
    GemmP pw{};
    pw.A = Qb4; pw.sAm = 1024; pw.K = 1024;
    pw.B = WoL; pw.sBn = 1024;
    pw.biasN = wo_b + (size_t)l * 1024;
    pw.C = xf; pw.cdtype = 3;
    pw.sCm = 1024; pw.sCn = 1; pw.scale = 1.f;
    gemm8<<<dim3(64, 4, 1), 512, 0, stream>>>(pw);

    add_ln_kernel<<<16384, 256, 0, stream>>>(xf, xd, ln1_g + (size_t)l * 1024,
                                             ln1_b + (size_t)l * 1024);

    // ---- FFN, row-chunked
    for (int r0 = 0; r0 < 16384; r0 += rowc) {
      GemmP f1{};
      f1.A = xd + (size_t)r0 * 1024; f1.sAm = 1024; f1.K = 1024;
      f1.B = F1L; f1.sBn = 1024;
      f1.C = R; f1.sCm = 4096; f1.sCn = 1;
      f1.biasN = ff_b1 + (size_t)l * 4096; f1.scale = 1.f; f1.relu = 1; f1.cdtype = 0;
      gemm8<<<dim3(rowc / 256, 16, 1), 512, 0, stream>>>(f1);

      GemmP f2{};
      f2.A = (unsigned short*)R; f2.sAm = 4096; f2.K = 4096;
      f2.B = F2L; f2.sBn = 4096;
      f2.biasN = ff_b2 + (size_t)l * 1024;
      f2.C = xf + (size_t)r0 * 1024; f2.cdtype = 3;
      f2.sCm = 1024; f2.sCn = 1; f2.scale = 1.f;
      gemm8<<<dim3(rowc / 256, 4, 1), 512, 0, stream>>>(f2);
    }
    // final LN of the net: bf16 copy not needed afterwards
    unsigned short* xdn = (l == 1) ? nullptr : xd;
    add_ln_kernel<<<16384, 256, 0, stream>>>(xf, xdn, ln2_g + (size_t)l * 1024,
                                             ln2_b + (size_t)l * 1024);
  }
}

// Round 9
// 1554.572 us; speedup vs baseline: 1.1253x; 1.1253x over previous
//
#include <hip/hip_runtime.h>
#include <hip/hip_bf16.h>
#include <hip/hip_fp16.h>

typedef __attribute__((ext_vector_type(8))) short short8;
typedef __attribute__((ext_vector_type(4))) float f32x4;

__device__ __forceinline__ unsigned short dev_f2bf(float f) {
  __hip_bfloat16 b = __float2bfloat16(f);
  union { __hip_bfloat16 b; unsigned short u; } c; c.b = b; return c.u;
}
__device__ __forceinline__ float dev_bf2f(unsigned short u) {
  union { unsigned int i; float f; } c; c.i = ((unsigned int)u) << 16; return c.f;
}

// async global->LDS, 16B per lane; dest = lds_base(wave-uniform) + lane*16
__device__ __forceinline__ void gload_lds16(const unsigned short* g, unsigned short* l) {
  __builtin_amdgcn_global_load_lds(
      (const __attribute__((address_space(1))) void*)(const void*)g,
      (__attribute__((address_space(3))) void*)(void*)l, 16, 0, 0);
}

struct GemmP {
  const unsigned short* A;   // bf16 bits
  const unsigned short* B;   // bf16 bits
  void* C;
  const float* biasN;        // bias by output col, may be null
  const float* biasM;        // bias by output row, may be null
  long long aHi, aLo, bHi, bLo, cHi, cLo;  // per-z base: (z>>4)*Hi + (z&15)*Lo
  int K;
  int sAm;                   // A row stride (k stride == 1)
  int sBn;                   // B row stride (k stride == 1)
  int sCm, sCn;
  float scale;
  int relu;
  int cdtype;                // 0=bf16, 1=f32, 3=f32 +=
};

// ---------------------------------------------------------------------------
// Big-GEMM: 256x256 tile, 512 threads (8 waves, 2Mx4N), BK=64, double-buffered
// LDS with counted vmcnt pipeline (never drains to 0 in main loop).
// LDS(row, c16) holds global(row, c16 ^ (row&7)); reads apply the same XOR.
// XCD swizzle (nwg%8==0): A-GROUPED decode (m = id/gy): each XCD works a
// contiguous band of M with all N -> A panel L2-resident, minimizes FETCH.
// Requires: M%256==0, N%256==0, K%64==0, K>=128, k-contiguous A/B, sCn==1.
// ---------------------------------------------------------------------------
__global__ __launch_bounds__(512, 2) void gemm256(GemmP p) {
  __shared__ __align__(16) unsigned short lds[2][2][256 * 64];  // 128 KiB

  const int tid = threadIdx.x;
  const int lane = tid & 63;
  const int wid = tid >> 6;       // 0..7
  const int wm = wid >> 2;        // 0..1
  const int wn = wid & 3;         // 0..3

  int id = blockIdx.y * gridDim.x + blockIdx.x;
  const int nwg = gridDim.x * gridDim.y;
  if ((nwg & 7) == 0) id = (id & 7) * (nwg >> 3) + (id >> 3);
  const long long m0 = (long long)(id / gridDim.y) * 256;   // A-grouped decode
  const long long n0 = (long long)(id % gridDim.y) * 256;

  const int srow8 = lane >> 3;                 // 0..7
  const int scol = ((lane & 7) ^ srow8) * 8;   // swizzled short offset

  f32x4 acc[8][4];
#pragma unroll
  for (int i = 0; i < 8; i++)
#pragma unroll
    for (int j = 0; j < 4; j++)
      acc[i][j] = f32x4{0.f, 0.f, 0.f, 0.f};

  const int nt = p.K >> 6;

  auto stage = [&](int buf, int t) {
    const long long k0 = (long long)t * 64;
#pragma unroll
    for (int h = 0; h < 4; h++)
      gload_lds16(p.A + (m0 + h * 64 + wid * 8 + srow8) * p.sAm + k0 + scol,
                  &lds[buf][0][(h * 64 + wid * 8) * 64]);
#pragma unroll
    for (int h = 0; h < 4; h++)
      gload_lds16(p.B + (n0 + h * 64 + wid * 8 + srow8) * p.sBn + k0 + scol,
                  &lds[buf][1][(h * 64 + wid * 8) * 64]);
  };

  stage(0, 0);
  stage(1, 1);

  for (int t = 0; t < nt; t++) {
    const int cur = t & 1;
    if (t + 1 < nt) asm volatile("s_waitcnt vmcnt(8)" ::: "memory");
    else            asm volatile("s_waitcnt vmcnt(0)" ::: "memory");
    __builtin_amdgcn_s_barrier();
    __builtin_amdgcn_sched_barrier(0);

    const unsigned short* Asb = lds[cur][0];
    const unsigned short* Bsb = lds[cur][1];
#pragma unroll
    for (int ks = 0; ks < 2; ks++) {
      const int c16 = ks * 4 + (lane >> 4);
      short8 a[8], b[4];
#pragma unroll
      for (int i = 0; i < 8; i++) {
        const int r = wm * 128 + i * 16 + (lane & 15);
        a[i] = *(const short8*)&Asb[r * 64 + ((c16 ^ (r & 7)) << 3)];
      }
#pragma unroll
      for (int j = 0; j < 4; j++) {
        const int r = wn * 64 + j * 16 + (lane & 15);
        b[j] = *(const short8*)&Bsb[r * 64 + ((c16 ^ (r & 7)) << 3)];
      }
      __builtin_amdgcn_s_setprio(1);
#pragma unroll
      for (int i = 0; i < 8; i++)
#pragma unroll
        for (int j = 0; j < 4; j++)
          acc[i][j] = __builtin_amdgcn_mfma_f32_16x16x32_bf16(a[i], b[j], acc[i][j], 0, 0, 0);
      __builtin_amdgcn_s_setprio(0);
    }
    __builtin_amdgcn_sched_barrier(0);
    __builtin_amdgcn_s_barrier();
    __builtin_amdgcn_sched_barrier(0);
    if (t + 2 < nt) stage(cur, t + 2);
  }

#pragma unroll
  for (int i = 0; i < 8; i++) {
#pragma unroll
    for (int j = 0; j < 4; j++) {
      const int col = (int)n0 + wn * 64 + j * 16 + (lane & 15);
      float bn = p.biasN ? p.biasN[col] : 0.f;
#pragma unroll
      for (int r = 0; r < 4; r++) {
        const long long row = m0 + wm * 128 + i * 16 + ((lane >> 4) << 2) + r;
        float v = acc[i][j][r] * p.scale + bn;
        if (p.relu) v = fmaxf(v, 0.f);
        const long long addr = row * p.sCm + col;
        if (p.cdtype == 0)      ((unsigned short*)p.C)[addr] = dev_f2bf(v);
        else if (p.cdtype == 3) ((float*)p.C)[addr] += v;
        else                    ((float*)p.C)[addr] = v;
      }
    }
  }
}

// ---------------------------------------------------------------------------
// Fused scores+softmax: per block 128 Q-rows x all 256 k of one head.
// S = 0.125 * Q[b,:,h*64:+64] @ EK[z]^T in f32 acc; row softmax via 16-lane
// shuffle reduce + cross-wave LDS reduce; writes P bf16 to [z][n][256].
// ---------------------------------------------------------------------------
__global__ __launch_bounds__(256, 2) void score_softmax_kernel(
    const unsigned short* __restrict__ Q, const unsigned short* __restrict__ EK,
    unsigned short* __restrict__ P) {
  __shared__ __align__(16) unsigned short As[128 * 64];
  __shared__ __align__(16) unsigned short Bs[256 * 64];
  __shared__ float red[2][2][128];   // [max|sum][wn][row]

  const int tid = threadIdx.x;
  const int lane = tid & 63;
  const int wid = tid >> 6;
  const int wm = wid >> 1, wn = wid & 1;   // 2x2 wave grid
  const int m0 = blockIdx.x * 128;
  const int z = blockIdx.z;
  const unsigned short* Ag = Q + (long long)(z >> 4) * 4194304 + (long long)(z & 15) * 64;
  const unsigned short* Bg = EK + (long long)z * 16384;

  const int srow = tid >> 3;
  const int scol = ((tid & 7) ^ (srow & 7)) * 8;

#pragma unroll
  for (int i = 0; i < 4; i++)
    gload_lds16(Ag + (long long)(m0 + i * 32 + srow) * 1024 + scol, &As[i * 2048 + wid * 512]);
#pragma unroll
  for (int i = 0; i < 8; i++)
    gload_lds16(Bg + (long long)(i * 32 + srow) * 64 + scol, &Bs[i * 2048 + wid * 512]);
  __syncthreads();

  f32x4 acc[4][8];
#pragma unroll
  for (int i = 0; i < 4; i++)
#pragma unroll
    for (int j = 0; j < 8; j++)
      acc[i][j] = f32x4{0.f, 0.f, 0.f, 0.f};

#pragma unroll
  for (int ks = 0; ks < 2; ks++) {
    const int c16 = ks * 4 + (lane >> 4);
    short8 a[4], b[8];
#pragma unroll
    for (int i = 0; i < 4; i++) {
      const int row = wm * 64 + i * 16 + (lane & 15);
      a[i] = *(const short8*)&As[row * 64 + ((c16 ^ (row & 7)) << 3)];
    }
#pragma unroll
    for (int j = 0; j < 8; j++) {
      const int row = wn * 128 + j * 16 + (lane & 15);
      b[j] = *(const short8*)&Bs[row * 64 + ((c16 ^ (row & 7)) << 3)];
    }
#pragma unroll
    for (int i = 0; i < 4; i++)
#pragma unroll
      for (int j = 0; j < 8; j++)
        acc[i][j] = __builtin_amdgcn_mfma_f32_16x16x32_bf16(a[i], b[j], acc[i][j], 0, 0, 0);
  }

  const int rr4 = (lane >> 4) << 2;
  // row partial max (this wave's 128 cols)
#pragma unroll
  for (int i = 0; i < 4; i++) {
#pragma unroll
    for (int r = 0; r < 4; r++) {
      float m = acc[i][0][r];
#pragma unroll
      for (int j = 1; j < 8; j++) m = fmaxf(m, acc[i][j][r]);
      m = fmaxf(m, __shfl_xor(m, 1));
      m = fmaxf(m, __shfl_xor(m, 2));
      m = fmaxf(m, __shfl_xor(m, 4));
      m = fmaxf(m, __shfl_xor(m, 8));
      if ((lane & 15) == 0) red[0][wn][wm * 64 + i * 16 + rr4 + r] = m;
    }
  }
  __syncthreads();
  float fm[4][4];
#pragma unroll
  for (int i = 0; i < 4; i++)
#pragma unroll
    for (int r = 0; r < 4; r++) {
      const int row = wm * 64 + i * 16 + rr4 + r;
      fm[i][r] = fmaxf(red[0][0][row], red[0][1][row]);
    }
  // exp + partial sum
#pragma unroll
  for (int i = 0; i < 4; i++) {
#pragma unroll
    for (int r = 0; r < 4; r++) {
      float s = 0.f;
#pragma unroll
      for (int j = 0; j < 8; j++) {
        float e = __expf((acc[i][j][r] - fm[i][r]) * 0.125f);
        acc[i][j][r] = e;
        s += e;
      }
      s += __shfl_xor(s, 1);
      s += __shfl_xor(s, 2);
      s += __shfl_xor(s, 4);
      s += __shfl_xor(s, 8);
      if ((lane & 15) == 0) red[1][wn][wm * 64 + i * 16 + rr4 + r] = s;
    }
  }
  __syncthreads();
  unsigned short* Pz = P + (long long)z * 1048576;
#pragma unroll
  for (int i = 0; i < 4; i++) {
#pragma unroll
    for (int r = 0; r < 4; r++) {
      const int row = wm * 64 + i * 16 + rr4 + r;
      const float inv = 1.f / (red[1][0][row] + red[1][1][row]);
#pragma unroll
      for (int j = 0; j < 8; j++) {
        const int col = wn * 128 + j * 16 + (lane & 15);
        Pz[(long long)(m0 + row) * 256 + col] = dev_f2bf(acc[i][j][r] * inv);
      }
    }
  }
}

// General NT GEMM (small/batched shapes): C[z,m,n] = scale*sum_k A[m,k]*B[n,k]
template<int BM, int BN, int WM, int WN>
__global__ __launch_bounds__(256, 2) void gemm_nt(GemmP p) {
  constexpr int BK = 64;
  constexpr int TM = BM / WM, TN = BN / WN;
  constexpr int FM = TM / 16, FN = TN / 16;
  __shared__ __align__(16) unsigned short As[BM * BK];
  __shared__ __align__(16) unsigned short Bs[BN * BK];

  const int tid = threadIdx.x;
  const int lane = tid & 63;
  const int wid = tid >> 6;
  const int wm = wid / WN, wn = wid % WN;
  const int m0 = blockIdx.x * BM;
  const int n0 = blockIdx.y * BN;
  const int z = blockIdx.z;
  const int zq = z >> 4, zr = z & 15;
  const unsigned short* Ag = p.A + (long long)zq * p.aHi + (long long)zr * p.aLo;
  const unsigned short* Bg = p.B + (long long)zq * p.bHi + (long long)zr * p.bLo;

  const int srow = tid >> 3;                      // 0..31
  const int scol = ((tid & 7) ^ (srow & 7)) * 8;  // swizzled 16B column
  constexpr int AC = BM / 32, BC = BN / 32;

  f32x4 acc[FM][FN];
#pragma unroll
  for (int i = 0; i < FM; i++)
#pragma unroll
    for (int j = 0; j < FN; j++)
      acc[i][j] = f32x4{0.f, 0.f, 0.f, 0.f};

  for (int k0 = 0; k0 < p.K; k0 += BK) {
#pragma unroll
    for (int i = 0; i < AC; i++)
      gload_lds16(Ag + (long long)(m0 + i * 32 + srow) * p.sAm + (k0 + scol),
                  &As[i * 2048 + wid * 512]);
#pragma unroll
    for (int i = 0; i < BC; i++)
      gload_lds16(Bg + (long long)(n0 + i * 32 + srow) * p.sBn + (k0 + scol),
                  &Bs[i * 2048 + wid * 512]);
    __syncthreads();
#pragma unroll
    for (int ks = 0; ks < 2; ks++) {
      const int c16 = ks * 4 + (lane >> 4);
      short8 a[FM], b[FN];
#pragma unroll
      for (int i = 0; i < FM; i++) {
        const int row = wm * TM + i * 16 + (lane & 15);
        a[i] = *(const short8*)&As[row * 64 + ((c16 ^ (row & 7)) << 3)];
      }
#pragma unroll
      for (int j = 0; j < FN; j++) {
        const int row = wn * TN + j * 16 + (lane & 15);
        b[j] = *(const short8*)&Bs[row * 64 + ((c16 ^ (row & 7)) << 3)];
      }
#pragma unroll
      for (int i = 0; i < FM; i++)
#pragma unroll
        for (int j = 0; j < FN; j++)
          acc[i][j] = __builtin_amdgcn_mfma_f32_16x16x32_bf16(a[i], b[j], acc[i][j], 0, 0, 0);
    }
    __syncthreads();
  }

  const long long zc_ = (long long)zq * p.cHi + (long long)zr * p.cLo;
#pragma unroll
  for (int i = 0; i < FM; i++) {
#pragma unroll
    for (int j = 0; j < FN; j++) {
      const int col = n0 + wn * TN + j * 16 + (lane & 15);
      float bn = p.biasN ? p.biasN[col] : 0.f;
#pragma unroll
      for (int r = 0; r < 4; r++) {
        const int row = m0 + wm * TM + i * 16 + ((lane >> 4) << 2) + r;
        float v = acc[i][j][r] * p.scale + bn;
        if (p.biasM) v += p.biasM[row];
        if (p.relu) v = fmaxf(v, 0.f);
        const long long addr = zc_ + (long long)row * p.sCm + (long long)col * p.sCn;
        if (p.cdtype == 0)      ((unsigned short*)p.C)[addr] = dev_f2bf(v);
        else if (p.cdtype == 3) ((float*)p.C)[addr] += v;
        else                    ((float*)p.C)[addr] = v;
      }
    }
  }
}

// 64x64 tiled transpose: in [b][4096][1024] -> out [b][1024][4096] (bf16)
__global__ __launch_bounds__(256) void transpose_kernel(const unsigned short* __restrict__ in,
                                                        unsigned short* __restrict__ out) {
  __shared__ unsigned short t[64][72];
  const int b = blockIdx.z;
  const int n0 = blockIdx.x * 64, c0 = blockIdx.y * 64;
  const int r = threadIdx.x >> 2;          // 0..63
  const int cc = (threadIdx.x & 3) * 16;   // 0,16,32,48
  const unsigned short* ip = in + (size_t)b * 4194304 + (size_t)n0 * 1024 + c0;
  *(short8*)&t[r][cc]     = *(const short8*)(ip + (size_t)r * 1024 + cc);
  *(short8*)&t[r][cc + 8] = *(const short8*)(ip + (size_t)r * 1024 + cc + 8);
  __syncthreads();
  unsigned short* op = out + (size_t)b * 4194304 + (size_t)c0 * 4096 + n0;
  short8 w0, w1;
#pragma unroll
  for (int j = 0; j < 8; j++) {
    w0[j] = (short)t[cc + j][r];
    w1[j] = (short)t[cc + 8 + j][r];
  }
  *(short8*)(op + (size_t)r * 4096 + cc)     = w0;
  *(short8*)(op + (size_t)r * 4096 + cc + 8) = w1;
}

// f32 -> bf16 (optionally also copy raw f32), x4 vectorized, grid-stride
__global__ void cvt_kernel(const float* __restrict__ src, unsigned short* __restrict__ dst,
                           float* __restrict__ dstf, long long n4) {
  long long i = (long long)blockIdx.x * blockDim.x + threadIdx.x;
  const long long stride = (long long)gridDim.x * blockDim.x;
  for (; i < n4; i += stride) {
    float4 v = ((const float4*)src)[i];
    ushort4 u;
    u.x = dev_f2bf(v.x); u.y = dev_f2bf(v.y); u.z = dev_f2bf(v.z); u.w = dev_f2bf(v.w);
    ((ushort4*)dst)[i] = u;
    if (dstf) ((float4*)dstf)[i] = v;
  }
}

// LN over rows of 1024 of xf (f32, holds x+y). Writes LN to xf and bf16 to xd (if xd).
__global__ __launch_bounds__(256) void add_ln_kernel(float* __restrict__ xf,
    unsigned short* __restrict__ xd,
    const float* __restrict__ g, const float* __restrict__ b) {
  const long long row = blockIdx.x;
  const int tid = threadIdx.x;
  float4 t = ((const float4*)(xf + row * 1024))[tid];
  float s = t.x + t.y + t.z + t.w;
  float ss = t.x * t.x + t.y * t.y + t.z * t.z + t.w * t.w;
#pragma unroll
  for (int off = 32; off > 0; off >>= 1) { s += __shfl_xor(s, off); ss += __shfl_xor(ss, off); }
  __shared__ float sm[8];
  const int wid = tid >> 6, lane = tid & 63;
  if (lane == 0) { sm[wid] = s; sm[4 + wid] = ss; }
  __syncthreads();
  s = sm[0] + sm[1] + sm[2] + sm[3];
  ss = sm[4] + sm[5] + sm[6] + sm[7];
  const float mean = s * (1.f / 1024.f);
  const float var = ss * (1.f / 1024.f) - mean * mean;
  const float rs = rsqrtf(var + 1e-5f);
  float4 gv = ((const float4*)g)[tid];
  float4 bv = ((const float4*)b)[tid];
  float4 o = {(t.x - mean) * rs * gv.x + bv.x, (t.y - mean) * rs * gv.y + bv.y,
              (t.z - mean) * rs * gv.z + bv.z, (t.w - mean) * rs * gv.w + bv.w};
  ((float4*)(xf + row * 1024))[tid] = o;
  if (xd) {
    ushort4 ob;
    ob.x = dev_f2bf(o.x); ob.y = dev_f2bf(o.y); ob.z = dev_f2bf(o.z); ob.w = dev_f2bf(o.w);
    ((ushort4*)(xd + row * 1024))[tid] = ob;
  }
}

// canary: unambiguous "workspace too small" signal (absmax ~ 100+max|ref|)
__global__ void fill_canary_kernel(float* p, long long n) {
  long long i = (long long)blockIdx.x * blockDim.x + threadIdx.x;
  const long long stride = (long long)gridDim.x * blockDim.x;
  for (; i < n; i += stride) p[i] = 100.0f;
}

extern "C" void kernel_launch(void* const* d_in, const int* in_sizes, int n_in,
                              void* d_out, int out_size, void* d_ws, size_t ws_size,
                              hipStream_t stream) {
  const float* x_in  = (const float*)d_in[0];
  const float* E_w   = (const float*)d_in[1];
  const float* E_b   = (const float*)d_in[2];
  const float* Wq    = (const float*)d_in[3];
  const float* Wk    = (const float*)d_in[4];
  const float* Wv    = (const float*)d_in[5];
  const float* wo_w  = (const float*)d_in[6];
  const float* wo_b  = (const float*)d_in[7];
  const float* ln1_g = (const float*)d_in[8];
  const float* ln1_b = (const float*)d_in[9];
  const float* ff_w1 = (const float*)d_in[10];
  const float* ff_b1 = (const float*)d_in[11];
  const float* ff_w2 = (const float*)d_in[12];
  const float* ff_b2 = (const float*)d_in[13];
  const float* ln2_g = (const float*)d_in[14];
  const float* ln2_b = (const float*)d_in[15];

  float* xf = (float*)d_out;   // f32 residual master lives in d_out

  char* ws = (char*)d_ws;
  size_t off = 0;
  auto alloc = [&](size_t bytes) -> char* {
    char* p = ws + off;
    off = (off + bytes + 255) & ~(size_t)255;
    return p;
  };
  unsigned short* E16 = (unsigned short*)alloc(1048576ULL * 2);  // E_w bf16 [256,4096]
  unsigned short* WqL = (unsigned short*)alloc(1048576ULL * 2);  // per-layer slices
  unsigned short* WkL = (unsigned short*)alloc(1048576ULL * 2);
  unsigned short* WvL = (unsigned short*)alloc(1048576ULL * 2);
  unsigned short* WoL = (unsigned short*)alloc(1048576ULL * 2);
  unsigned short* F1L = (unsigned short*)alloc(4194304ULL * 2);
  unsigned short* F2L = (unsigned short*)alloc(4194304ULL * 2);
  unsigned short* xE  = (unsigned short*)alloc(1048576ULL * 2);  // [b][256][1024]
  unsigned short* EK  = (unsigned short*)alloc(1048576ULL * 2);  // [z][256][64]
  unsigned short* EVt = (unsigned short*)alloc(1048576ULL * 2);  // [z][64][256]
  unsigned short* xd  = (unsigned short*)alloc(16777216ULL * 2); // bf16 working x
  unsigned short* xT  = (unsigned short*)alloc(16777216ULL * 2); // x^T [b][1024][4096]; later Q/cat
  unsigned short* Qb4 = xT;   // alias: xT dead once pe is done; Q/cat [16384][1024]

  size_t rem = (ws_size > off) ? ws_size - off : 0;
  size_t Rbytes = rem > 512 ? rem - 512 : 0;
  if (Rbytes > 134217728ULL) Rbytes = 134217728ULL;
  int zc = 64;     // heads-chunk over z=0..63 (P chunk = zc * 2 MiB)
  while (zc > 1 && (size_t)zc * 2097152ULL > Rbytes) zc >>= 1;
  int rowc = 16384;
  while (rowc > 256 && (size_t)rowc * 8192ULL > Rbytes) rowc >>= 1;
  if ((size_t)zc * 2097152ULL > Rbytes || (size_t)rowc * 8192ULL > Rbytes) {
    fill_canary_kernel<<<2048, 256, 0, stream>>>(xf, (long long)out_size);
    return;
  }
  char* R = alloc(Rbytes);

  auto cvt = [&](const float* s, unsigned short* d, float* df, long long n) {
    long long n4 = n / 4;
    int grid = (int)((n4 + 255) / 256);
    if (grid > 4096) grid = 4096;
    cvt_kernel<<<grid, 256, 0, stream>>>(s, d, df, n4);
  };

  cvt(x_in, xd, xf, 16777216);     // x: bf16 into ws, f32 master into d_out
  cvt(E_w, E16, nullptr, 1048576);

  for (int l = 0; l < 2; l++) {
    cvt(Wq + (size_t)l * 1048576, WqL, nullptr, 1048576);
    cvt(Wk + (size_t)l * 1048576, WkL, nullptr, 1048576);
    cvt(Wv + (size_t)l * 1048576, WvL, nullptr, 1048576);
    cvt(wo_w + (size_t)l * 1048576, WoL, nullptr, 1048576);
    cvt(ff_w1 + (size_t)l * 4194304, F1L, nullptr, 4194304);
    cvt(ff_w2 + (size_t)l * 4194304, F2L, nullptr, 4194304);

    // ---- xT[b][c][n] = x[b][n][c]
    transpose_kernel<<<dim3(64, 16, 4), 256, 0, stream>>>(xd, xT);

    // ---- xE[b][k][c] = sum_n E_w[k,n] * xT[b][c][n]   (pure NT, z = b)
    GemmP pe{};
    pe.A = E16; pe.sAm = 4096; pe.K = 4096;
    pe.B = xT; pe.sBn = 4096; pe.bLo = 4194304;
    pe.C = xE; pe.cLo = 262144; pe.sCm = 1024; pe.sCn = 1;
    pe.scale = 1.f; pe.cdtype = 0;
    gemm_nt<64,128,2,2><<<dim3(4, 8, 4), 256, 0, stream>>>(pe);

    // ---- EK[z][k][d] = xE[b] @ Wk[h]^T + E_b[k]   (z = b*16+h)
    GemmP pk{};
    pk.A = xE; pk.sAm = 1024; pk.K = 1024; pk.aHi = 262144; pk.aLo = 0;
    pk.B = WkL; pk.sBn = 1024; pk.bHi = 0; pk.bLo = 65536;
    pk.C = EK; pk.cHi = 262144; pk.cLo = 16384; pk.sCm = 64; pk.sCn = 1;
    pk.biasM = E_b; pk.scale = 1.f; pk.cdtype = 0;
    gemm_nt<64,64,2,2><<<dim3(4, 1, 64), 256, 0, stream>>>(pk);
    // ---- EVt[z][d][k] = (xE[b] @ Wv[h]^T + E_b[k])^T
    GemmP pv2 = pk;
    pv2.B = WvL; pv2.C = EVt; pv2.sCm = 1; pv2.sCn = 256;
    gemm_nt<64,64,2,2><<<dim3(4, 1, 64), 256, 0, stream>>>(pv2);

    // ---- Q (all batches) = x @ Wq^T : [16384,1024]   (overwrites xT region)
    GemmP pq{};
    pq.A = xd; pq.sAm = 1024; pq.K = 1024;
    pq.B = WqL; pq.sBn = 1024;
    pq.C = Qb4; pq.sCm = 1024; pq.sCn = 1;
    pq.scale = 1.f; pq.cdtype = 0;
    gemm256<<<dim3(64, 4, 1), 512, 0, stream>>>(pq);

    for (int z0 = 0; z0 < 64; z0 += zc) {
      const long long aOff = (long long)(z0 >> 4) * 4194304 + (long long)(z0 & 15) * 64;
      const long long eOff = (long long)z0 * 16384;
      // ---- P[zl][n][k] = softmax(0.125 * Q @ EK^T)  (fused, bf16)
      score_softmax_kernel<<<dim3(32, 1, zc), 256, 0, stream>>>(
          Qb4 + aOff, EK + eOff, (unsigned short*)R);

      // ---- attn = P @ EVt^T -> cat[b][n][h*64+d]  (cat aliases Qb4; per-z col slice)
      GemmP pp{};
      pp.A = (unsigned short*)R; pp.aHi = 16777216; pp.aLo = 1048576; pp.sAm = 256; pp.K = 256;
      pp.B = EVt + eOff; pp.bHi = 262144; pp.bLo = 16384; pp.sBn = 256;
      pp.C = Qb4 + aOff; pp.cHi = 4194304; pp.cLo = 64; pp.sCm = 1024; pp.sCn = 1;
      pp.scale = 1.f; pp.cdtype = 0;
      gemm_nt<128,64,4,1><<<dim3(32, 1, zc), 256, 0, stream>>>(pp);
    }

    // ---- xf += cat @ wo^T + wo_b   (f32 accumulate epilogue, all batches)
    GemmP pw{};
    pw.A = Qb4; pw.sAm = 1024; pw.K = 1024;
    pw.B = WoL; pw.sBn = 1024;
    pw.biasN = wo_b + (size_t)l * 1024;
    pw.C = xf; pw.cdtype = 3;
    pw.sCm = 1024; pw.sCn = 1; pw.scale = 1.f;
    gemm256<<<dim3(64, 4, 1), 512, 0, stream>>>(pw);

    add_ln_kernel<<<16384, 256, 0, stream>>>(xf, xd, ln1_g + (size_t)l * 1024,
                                             ln1_b + (size_t)l * 1024);

    // ---- FFN, row-chunked
    for (int r0 = 0; r0 < 16384; r0 += rowc) {
      GemmP f1{};
      f1.A = xd + (size_t)r0 * 1024; f1.sAm = 1024; f1.K = 1024;
      f1.B = F1L; f1.sBn = 1024;
      f1.C = R; f1.sCm = 4096; f1.sCn = 1;
      f1.biasN = ff_b1 + (size_t)l * 4096; f1.scale = 1.f; f1.relu = 1; f1.cdtype = 0;
      gemm256<<<dim3(rowc / 256, 16, 1), 512, 0, stream>>>(f1);

      GemmP f2{};
      f2.A = (unsigned short*)R; f2.sAm = 4096; f2.K = 4096;
      f2.B = F2L; f2.sBn = 4096;
      f2.biasN = ff_b2 + (size_t)l * 1024;
      f2.C = xf + (size_t)r0 * 1024; f2.cdtype = 3;
      f2.sCm = 1024; f2.sCn = 1; f2.scale = 1.f;
      gemm256<<<dim3(rowc / 256, 4, 1), 512, 0, stream>>>(f2);
    }
    // final LN of the net: bf16 copy not needed afterwards
    unsigned short* xdn = (l == 1) ? nullptr : xd;
    add_ln_kernel<<<16384, 256, 0, stream>>>(xf, xdn, ln2_g + (size_t)l * 1024,
                                             ln2_b + (size_t)l * 1024);
  }
}

// Round 10
// 1552.552 us; speedup vs baseline: 1.1268x; 1.0013x over previous
//
#include <hip/hip_runtime.h>
#include <hip/hip_bf16.h>

typedef __attribute__((ext_vector_type(8))) short short8;
typedef __attribute__((ext_vector_type(4))) float f32x4;

__device__ __forceinline__ unsigned short dev_f2bf(float f) {
  __hip_bfloat16 b = __float2bfloat16(f);
  union { __hip_bfloat16 b; unsigned short u; } c; c.b = b; return c.u;
}
__device__ __forceinline__ float dev_bf2f(unsigned short u) {
  union { unsigned int i; float f; } c; c.i = ((unsigned int)u) << 16; return c.f;
}

// async global->LDS, 16B per lane; dest = lds_base(wave-uniform) + lane*16
__device__ __forceinline__ void gload_lds16(const unsigned short* g, unsigned short* l) {
  __builtin_amdgcn_global_load_lds(
      (const __attribute__((address_space(1))) void*)(const void*)g,
      (__attribute__((address_space(3))) void*)(void*)l, 16, 0, 0);
}

struct GemmP {
  const unsigned short* A;   // bf16 bits
  const unsigned short* B;   // bf16 bits
  void* C;
  const float* biasN;        // bias by output col, may be null
  const float* biasM;        // bias by output row, may be null
  long long aHi, aLo, bHi, bLo, cHi, cLo;  // per-z base: (z>>4)*Hi + (z&15)*Lo
  int K;
  int sAm;                   // A row stride (k stride == 1)
  int sBn;                   // B row stride (k stride == 1)
  int sCm, sCn;
  float scale;
  int relu;
  int cdtype;                // 0=bf16, 1=f32, 3=f32 +=
};

// ---------------------------------------------------------------------------
// Big-GEMM: 256x256 tile, 512 threads (8 waves, 2Mx4N), BK=64, double-buffered
// LDS with counted vmcnt pipeline (never drains to 0 in main loop).
// LDS(row, c16) holds global(row, c16 ^ (row&7)); reads apply the same XOR.
// XCD swizzle (nwg%8==0): A-GROUPED decode: each XCD works a contiguous band
// of M with all N -> A panel L2-resident, minimizes FETCH.
// ---------------------------------------------------------------------------
__global__ __launch_bounds__(512, 2) void gemm256(GemmP p) {
  __shared__ __align__(16) unsigned short lds[2][2][256 * 64];  // 128 KiB

  const int tid = threadIdx.x;
  const int lane = tid & 63;
  const int wid = tid >> 6;       // 0..7
  const int wm = wid >> 2;        // 0..1
  const int wn = wid & 3;         // 0..3

  int id = blockIdx.y * gridDim.x + blockIdx.x;
  const int nwg = gridDim.x * gridDim.y;
  if ((nwg & 7) == 0) id = (id & 7) * (nwg >> 3) + (id >> 3);
  const long long m0 = (long long)(id / gridDim.y) * 256;   // A-grouped decode
  const long long n0 = (long long)(id % gridDim.y) * 256;

  const int srow8 = lane >> 3;                 // 0..7
  const int scol = ((lane & 7) ^ srow8) * 8;   // swizzled short offset

  f32x4 acc[8][4];
#pragma unroll
  for (int i = 0; i < 8; i++)
#pragma unroll
    for (int j = 0; j < 4; j++)
      acc[i][j] = f32x4{0.f, 0.f, 0.f, 0.f};

  const int nt = p.K >> 6;

  auto stage = [&](int buf, int t) {
    const long long k0 = (long long)t * 64;
#pragma unroll
    for (int h = 0; h < 4; h++)
      gload_lds16(p.A + (m0 + h * 64 + wid * 8 + srow8) * p.sAm + k0 + scol,
                  &lds[buf][0][(h * 64 + wid * 8) * 64]);
#pragma unroll
    for (int h = 0; h < 4; h++)
      gload_lds16(p.B + (n0 + h * 64 + wid * 8 + srow8) * p.sBn + k0 + scol,
                  &lds[buf][1][(h * 64 + wid * 8) * 64]);
  };

  stage(0, 0);
  stage(1, 1);

  for (int t = 0; t < nt; t++) {
    const int cur = t & 1;
    if (t + 1 < nt) asm volatile("s_waitcnt vmcnt(8)" ::: "memory");
    else            asm volatile("s_waitcnt vmcnt(0)" ::: "memory");
    __builtin_amdgcn_s_barrier();
    __builtin_amdgcn_sched_barrier(0);

    const unsigned short* Asb = lds[cur][0];
    const unsigned short* Bsb = lds[cur][1];
#pragma unroll
    for (int ks = 0; ks < 2; ks++) {
      const int c16 = ks * 4 + (lane >> 4);
      short8 a[8], b[4];
#pragma unroll
      for (int i = 0; i < 8; i++) {
        const int r = wm * 128 + i * 16 + (lane & 15);
        a[i] = *(const short8*)&Asb[r * 64 + ((c16 ^ (r & 7)) << 3)];
      }
#pragma unroll
      for (int j = 0; j < 4; j++) {
        const int r = wn * 64 + j * 16 + (lane & 15);
        b[j] = *(const short8*)&Bsb[r * 64 + ((c16 ^ (r & 7)) << 3)];
      }
      __builtin_amdgcn_s_setprio(1);
#pragma unroll
      for (int i = 0; i < 8; i++)
#pragma unroll
        for (int j = 0; j < 4; j++)
          acc[i][j] = __builtin_amdgcn_mfma_f32_16x16x32_bf16(a[i], b[j], acc[i][j], 0, 0, 0);
      __builtin_amdgcn_s_setprio(0);
    }
    __builtin_amdgcn_sched_barrier(0);
    __builtin_amdgcn_s_barrier();
    __builtin_amdgcn_sched_barrier(0);
    if (t + 2 < nt) stage(cur, t + 2);
  }

#pragma unroll
  for (int i = 0; i < 8; i++) {
#pragma unroll
    for (int j = 0; j < 4; j++) {
      const int col = (int)n0 + wn * 64 + j * 16 + (lane & 15);
      float bn = p.biasN ? p.biasN[col] : 0.f;
#pragma unroll
      for (int r = 0; r < 4; r++) {
        const long long row = m0 + wm * 128 + i * 16 + ((lane >> 4) << 2) + r;
        float v = acc[i][j][r] * p.scale + bn;
        if (p.relu) v = fmaxf(v, 0.f);
        const long long addr = row * p.sCm + col;
        if (p.cdtype == 0)      ((unsigned short*)p.C)[addr] = dev_f2bf(v);
        else if (p.cdtype == 3) ((float*)p.C)[addr] += v;
        else                    ((float*)p.C)[addr] = v;
      }
    }
  }
}

// ---------------------------------------------------------------------------
// Fully fused attention: per block = 128 q-rows x one head z.
// Phase 1: S = Q @ EK^T (f32 acc, 4 waves 2x2).  Phase 2: row softmax
// in-register (shuffle + cross-wave LDS reduce).  Phase 3: P -> LDS bf16
// with granule-XOR swizzle.  Phase 4: out = P @ EVt^T -> cat (in-place over
// the Q slice; each (m0,z) slice touched only by its own block).
// EVt staged via pre-swizzled-source global_load_lds issued at kernel start.
// ---------------------------------------------------------------------------
__global__ __launch_bounds__(256, 1) void attn_kernel(
    const unsigned short* __restrict__ Q, const unsigned short* __restrict__ EK,
    const unsigned short* __restrict__ EVt) {
  __shared__ __align__(16) unsigned short As[128 * 64];    // Q tile     16 KB
  __shared__ __align__(16) unsigned short Bs[256 * 64];    // EK         32 KB
  __shared__ __align__(16) unsigned short Vs[64 * 256];    // EVt        32 KB
  __shared__ __align__(16) unsigned short Ps[128 * 256];   // P          64 KB
  __shared__ float red[2][2][128];                         // max|sum     2 KB

  const int tid = threadIdx.x;
  const int lane = tid & 63;
  const int wid = tid >> 6;
  const int wm = wid >> 1, wn = wid & 1;   // 2x2 wave grid
  const int m0 = blockIdx.x * 128;
  const int z = blockIdx.z;
  unsigned short* Qz = (unsigned short*)Q + (long long)(z >> 4) * 4194304 + (long long)(z & 15) * 64;
  const unsigned short* EKz = EK + (long long)z * 16384;
  const unsigned short* EVz = EVt + (long long)z * 16384;

  const int srow = tid >> 3;
  const int scol = ((tid & 7) ^ (srow & 7)) * 8;

#pragma unroll
  for (int i = 0; i < 4; i++)
    gload_lds16(Qz + (long long)(m0 + i * 32 + srow) * 1024 + scol, &As[i * 2048 + wid * 512]);
#pragma unroll
  for (int i = 0; i < 8; i++)
    gload_lds16(EKz + (long long)(i * 32 + srow) * 64 + scol, &Bs[i * 2048 + wid * 512]);
  // EVt: 64 rows x 256 shorts; physical granule pg holds logical granule
  // (pg&31)^(d&7) of row d=pg>>5  -> pre-swizzled source, linear dest.
#pragma unroll
  for (int c = 0; c < 8; c++) {
    const int pg = (c * 4 + wid) * 64 + lane;
    const int d = pg >> 5, gp = pg & 31;
    gload_lds16(EVz + d * 256 + ((gp ^ (d & 7)) << 3), &Vs[(c * 4 + wid) * 512]);
  }
  __syncthreads();

  f32x4 acc[4][8];
#pragma unroll
  for (int i = 0; i < 4; i++)
#pragma unroll
    for (int j = 0; j < 8; j++)
      acc[i][j] = f32x4{0.f, 0.f, 0.f, 0.f};

#pragma unroll
  for (int ks = 0; ks < 2; ks++) {
    const int c16 = ks * 4 + (lane >> 4);
    short8 a[4], b[8];
#pragma unroll
    for (int i = 0; i < 4; i++) {
      const int row = wm * 64 + i * 16 + (lane & 15);
      a[i] = *(const short8*)&As[row * 64 + ((c16 ^ (row & 7)) << 3)];
    }
#pragma unroll
    for (int j = 0; j < 8; j++) {
      const int row = wn * 128 + j * 16 + (lane & 15);
      b[j] = *(const short8*)&Bs[row * 64 + ((c16 ^ (row & 7)) << 3)];
    }
#pragma unroll
    for (int i = 0; i < 4; i++)
#pragma unroll
      for (int j = 0; j < 8; j++)
        acc[i][j] = __builtin_amdgcn_mfma_f32_16x16x32_bf16(a[i], b[j], acc[i][j], 0, 0, 0);
  }

  const int rr4 = (lane >> 4) << 2;
#pragma unroll
  for (int i = 0; i < 4; i++) {
#pragma unroll
    for (int r = 0; r < 4; r++) {
      float m = acc[i][0][r];
#pragma unroll
      for (int j = 1; j < 8; j++) m = fmaxf(m, acc[i][j][r]);
      m = fmaxf(m, __shfl_xor(m, 1));
      m = fmaxf(m, __shfl_xor(m, 2));
      m = fmaxf(m, __shfl_xor(m, 4));
      m = fmaxf(m, __shfl_xor(m, 8));
      if ((lane & 15) == 0) red[0][wn][wm * 64 + i * 16 + rr4 + r] = m;
    }
  }
  __syncthreads();
  float fm[4][4];
#pragma unroll
  for (int i = 0; i < 4; i++)
#pragma unroll
    for (int r = 0; r < 4; r++) {
      const int row = wm * 64 + i * 16 + rr4 + r;
      fm[i][r] = fmaxf(red[0][0][row], red[0][1][row]);
    }
#pragma unroll
  for (int i = 0; i < 4; i++) {
#pragma unroll
    for (int r = 0; r < 4; r++) {
      float s = 0.f;
#pragma unroll
      for (int j = 0; j < 8; j++) {
        float e = __expf((acc[i][j][r] - fm[i][r]) * 0.125f);
        acc[i][j][r] = e;
        s += e;
      }
      s += __shfl_xor(s, 1);
      s += __shfl_xor(s, 2);
      s += __shfl_xor(s, 4);
      s += __shfl_xor(s, 8);
      if ((lane & 15) == 0) red[1][wn][wm * 64 + i * 16 + rr4 + r] = s;
    }
  }
  __syncthreads();
  // P -> LDS (bf16): Ps[row][ (g ^ (row&7)) granule ] = P[row][col]
#pragma unroll
  for (int i = 0; i < 4; i++) {
#pragma unroll
    for (int r = 0; r < 4; r++) {
      const int row = wm * 64 + i * 16 + rr4 + r;
      const float inv = 1.f / (red[1][0][row] + red[1][1][row]);
#pragma unroll
      for (int j = 0; j < 8; j++) {
        const int col = wn * 128 + j * 16 + (lane & 15);
        Ps[row * 256 + (((col >> 3) ^ (row & 7)) << 3) + (col & 7)] =
            dev_f2bf(acc[i][j][r] * inv);
      }
    }
  }
  __syncthreads();

  // Phase 4: out[q][d] = sum_k P[q,k] * EVt[d,k]; per wave 64q x 32d
  f32x4 acc2[4][2];
#pragma unroll
  for (int i = 0; i < 4; i++)
#pragma unroll
    for (int jj = 0; jj < 2; jj++)
      acc2[i][jj] = f32x4{0.f, 0.f, 0.f, 0.f};

#pragma unroll
  for (int ks = 0; ks < 8; ks++) {
    const int G = ks * 4 + (lane >> 4);
    short8 pa[4], pb[2];
#pragma unroll
    for (int i = 0; i < 4; i++) {
      const int row = wm * 64 + i * 16 + (lane & 15);
      pa[i] = *(const short8*)&Ps[row * 256 + ((G ^ (row & 7)) << 3)];
    }
#pragma unroll
    for (int jj = 0; jj < 2; jj++) {
      const int d = wn * 32 + jj * 16 + (lane & 15);
      pb[jj] = *(const short8*)&Vs[d * 256 + ((G ^ (d & 7)) << 3)];
    }
#pragma unroll
    for (int i = 0; i < 4; i++)
#pragma unroll
      for (int jj = 0; jj < 2; jj++)
        acc2[i][jj] = __builtin_amdgcn_mfma_f32_16x16x32_bf16(pa[i], pb[jj], acc2[i][jj], 0, 0, 0);
  }

#pragma unroll
  for (int i = 0; i < 4; i++) {
#pragma unroll
    for (int jj = 0; jj < 2; jj++) {
#pragma unroll
      for (int r = 0; r < 4; r++) {
        const int qrow = m0 + wm * 64 + i * 16 + rr4 + r;
        const int dcol = wn * 32 + jj * 16 + (lane & 15);
        Qz[(long long)qrow * 1024 + dcol] = dev_f2bf(acc2[i][jj][r]);
      }
    }
  }
}

// General NT GEMM (small/batched shapes): C[z,m,n] = scale*sum_k A[m,k]*B[n,k]
template<int BM, int BN, int WM, int WN>
__global__ __launch_bounds__(256, 2) void gemm_nt(GemmP p) {
  constexpr int BK = 64;
  constexpr int TM = BM / WM, TN = BN / WN;
  constexpr int FM = TM / 16, FN = TN / 16;
  __shared__ __align__(16) unsigned short As[BM * BK];
  __shared__ __align__(16) unsigned short Bs[BN * BK];

  const int tid = threadIdx.x;
  const int lane = tid & 63;
  const int wid = tid >> 6;
  const int wm = wid / WN, wn = wid % WN;
  const int m0 = blockIdx.x * BM;
  const int n0 = blockIdx.y * BN;
  const int z = blockIdx.z;
  const int zq = z >> 4, zr = z & 15;
  const unsigned short* Ag = p.A + (long long)zq * p.aHi + (long long)zr * p.aLo;
  const unsigned short* Bg = p.B + (long long)zq * p.bHi + (long long)zr * p.bLo;

  const int srow = tid >> 3;                      // 0..31
  const int scol = ((tid & 7) ^ (srow & 7)) * 8;  // swizzled 16B column
  constexpr int AC = BM / 32, BC = BN / 32;

  f32x4 acc[FM][FN];
#pragma unroll
  for (int i = 0; i < FM; i++)
#pragma unroll
    for (int j = 0; j < FN; j++)
      acc[i][j] = f32x4{0.f, 0.f, 0.f, 0.f};

  for (int k0 = 0; k0 < p.K; k0 += BK) {
#pragma unroll
    for (int i = 0; i < AC; i++)
      gload_lds16(Ag + (long long)(m0 + i * 32 + srow) * p.sAm + (k0 + scol),
                  &As[i * 2048 + wid * 512]);
#pragma unroll
    for (int i = 0; i < BC; i++)
      gload_lds16(Bg + (long long)(n0 + i * 32 + srow) * p.sBn + (k0 + scol),
                  &Bs[i * 2048 + wid * 512]);
    __syncthreads();
#pragma unroll
    for (int ks = 0; ks < 2; ks++) {
      const int c16 = ks * 4 + (lane >> 4);
      short8 a[FM], b[FN];
#pragma unroll
      for (int i = 0; i < FM; i++) {
        const int row = wm * TM + i * 16 + (lane & 15);
        a[i] = *(const short8*)&As[row * 64 + ((c16 ^ (row & 7)) << 3)];
      }
#pragma unroll
      for (int j = 0; j < FN; j++) {
        const int row = wn * TN + j * 16 + (lane & 15);
        b[j] = *(const short8*)&Bs[row * 64 + ((c16 ^ (row & 7)) << 3)];
      }
#pragma unroll
      for (int i = 0; i < FM; i++)
#pragma unroll
        for (int j = 0; j < FN; j++)
          acc[i][j] = __builtin_amdgcn_mfma_f32_16x16x32_bf16(a[i], b[j], acc[i][j], 0, 0, 0);
    }
    __syncthreads();
  }

  const long long zc_ = (long long)zq * p.cHi + (long long)zr * p.cLo;
#pragma unroll
  for (int i = 0; i < FM; i++) {
#pragma unroll
    for (int j = 0; j < FN; j++) {
      const int col = n0 + wn * TN + j * 16 + (lane & 15);
      float bn = p.biasN ? p.biasN[col] : 0.f;
#pragma unroll
      for (int r = 0; r < 4; r++) {
        const int row = m0 + wm * TM + i * 16 + ((lane >> 4) << 2) + r;
        float v = acc[i][j][r] * p.scale + bn;
        if (p.biasM) v += p.biasM[row];
        if (p.relu) v = fmaxf(v, 0.f);
        const long long addr = zc_ + (long long)row * p.sCm + (long long)col * p.sCn;
        if (p.cdtype == 0)      ((unsigned short*)p.C)[addr] = dev_f2bf(v);
        else if (p.cdtype == 3) ((float*)p.C)[addr] += v;
        else                    ((float*)p.C)[addr] = v;
      }
    }
  }
}

// 64x64 tiled transpose: in [b][4096][1024] -> out [b][1024][4096] (bf16)
__global__ __launch_bounds__(256) void transpose_kernel(const unsigned short* __restrict__ in,
                                                        unsigned short* __restrict__ out) {
  __shared__ unsigned short t[64][72];
  const int b = blockIdx.z;
  const int n0 = blockIdx.x * 64, c0 = blockIdx.y * 64;
  const int r = threadIdx.x >> 2;          // 0..63
  const int cc = (threadIdx.x & 3) * 16;   // 0,16,32,48
  const unsigned short* ip = in + (size_t)b * 4194304 + (size_t)n0 * 1024 + c0;
  *(short8*)&t[r][cc]     = *(const short8*)(ip + (size_t)r * 1024 + cc);
  *(short8*)&t[r][cc + 8] = *(const short8*)(ip + (size_t)r * 1024 + cc + 8);
  __syncthreads();
  unsigned short* op = out + (size_t)b * 4194304 + (size_t)c0 * 4096 + n0;
  short8 w0, w1;
#pragma unroll
  for (int j = 0; j < 8; j++) {
    w0[j] = (short)t[cc + j][r];
    w1[j] = (short)t[cc + 8 + j][r];
  }
  *(short8*)(op + (size_t)r * 4096 + cc)     = w0;
  *(short8*)(op + (size_t)r * 4096 + cc + 8) = w1;
}

// f32 -> bf16 (optionally also copy raw f32), x4 vectorized, grid-stride
__global__ void cvt_kernel(const float* __restrict__ src, unsigned short* __restrict__ dst,
                           float* __restrict__ dstf, long long n4) {
  long long i = (long long)blockIdx.x * blockDim.x + threadIdx.x;
  const long long stride = (long long)gridDim.x * blockDim.x;
  for (; i < n4; i += stride) {
    float4 v = ((const float4*)src)[i];
    ushort4 u;
    u.x = dev_f2bf(v.x); u.y = dev_f2bf(v.y); u.z = dev_f2bf(v.z); u.w = dev_f2bf(v.w);
    ((ushort4*)dst)[i] = u;
    if (dstf) ((float4*)dstf)[i] = v;
  }
}

// LN over rows of 1024 of xf (f32, holds x+y). Writes LN to xf and bf16 to xd (if xd).
__global__ __launch_bounds__(256) void add_ln_kernel(float* __restrict__ xf,
    unsigned short* __restrict__ xd,
    const float* __restrict__ g, const float* __restrict__ b) {
  const long long row = blockIdx.x;
  const int tid = threadIdx.x;
  float4 t = ((const float4*)(xf + row * 1024))[tid];
  float s = t.x + t.y + t.z + t.w;
  float ss = t.x * t.x + t.y * t.y + t.z * t.z + t.w * t.w;
#pragma unroll
  for (int off = 32; off > 0; off >>= 1) { s += __shfl_xor(s, off); ss += __shfl_xor(ss, off); }
  __shared__ float sm[8];
  const int wid = tid >> 6, lane = tid & 63;
  if (lane == 0) { sm[wid] = s; sm[4 + wid] = ss; }
  __syncthreads();
  s = sm[0] + sm[1] + sm[2] + sm[3];
  ss = sm[4] + sm[5] + sm[6] + sm[7];
  const float mean = s * (1.f / 1024.f);
  const float var = ss * (1.f / 1024.f) - mean * mean;
  const float rs = rsqrtf(var + 1e-5f);
  float4 gv = ((const float4*)g)[tid];
  float4 bv = ((const float4*)b)[tid];
  float4 o = {(t.x - mean) * rs * gv.x + bv.x, (t.y - mean) * rs * gv.y + bv.y,
              (t.z - mean) * rs * gv.z + bv.z, (t.w - mean) * rs * gv.w + bv.w};
  ((float4*)(xf + row * 1024))[tid] = o;
  if (xd) {
    ushort4 ob;
    ob.x = dev_f2bf(o.x); ob.y = dev_f2bf(o.y); ob.z = dev_f2bf(o.z); ob.w = dev_f2bf(o.w);
    ((ushort4*)(xd + row * 1024))[tid] = ob;
  }
}

// canary: unambiguous "workspace too small" signal (absmax ~ 100+max|ref|)
__global__ void fill_canary_kernel(float* p, long long n) {
  long long i = (long long)blockIdx.x * blockDim.x + threadIdx.x;
  const long long stride = (long long)gridDim.x * blockDim.x;
  for (; i < n; i += stride) p[i] = 100.0f;
}

extern "C" void kernel_launch(void* const* d_in, const int* in_sizes, int n_in,
                              void* d_out, int out_size, void* d_ws, size_t ws_size,
                              hipStream_t stream) {
  const float* x_in  = (const float*)d_in[0];
  const float* E_w   = (const float*)d_in[1];
  const float* E_b   = (const float*)d_in[2];
  const float* Wq    = (const float*)d_in[3];
  const float* Wk    = (const float*)d_in[4];
  const float* Wv    = (const float*)d_in[5];
  const float* wo_w  = (const float*)d_in[6];
  const float* wo_b  = (const float*)d_in[7];
  const float* ln1_g = (const float*)d_in[8];
  const float* ln1_b = (const float*)d_in[9];
  const float* ff_w1 = (const float*)d_in[10];
  const float* ff_b1 = (const float*)d_in[11];
  const float* ff_w2 = (const float*)d_in[12];
  const float* ff_b2 = (const float*)d_in[13];
  const float* ln2_g = (const float*)d_in[14];
  const float* ln2_b = (const float*)d_in[15];

  float* xf = (float*)d_out;   // f32 residual master lives in d_out

  char* ws = (char*)d_ws;
  size_t off = 0;
  auto alloc = [&](size_t bytes) -> char* {
    char* p = ws + off;
    off = (off + bytes + 255) & ~(size_t)255;
    return p;
  };
  unsigned short* E16 = (unsigned short*)alloc(1048576ULL * 2);  // E_w bf16 [256,4096]
  unsigned short* WqL = (unsigned short*)alloc(1048576ULL * 2);  // per-layer slices
  unsigned short* WkL = (unsigned short*)alloc(1048576ULL * 2);
  unsigned short* WvL = (unsigned short*)alloc(1048576ULL * 2);
  unsigned short* WoL = (unsigned short*)alloc(1048576ULL * 2);
  unsigned short* F1L = (unsigned short*)alloc(4194304ULL * 2);
  unsigned short* F2L = (unsigned short*)alloc(4194304ULL * 2);
  unsigned short* xE  = (unsigned short*)alloc(1048576ULL * 2);  // [b][256][1024]
  unsigned short* EK  = (unsigned short*)alloc(1048576ULL * 2);  // [z][256][64]
  unsigned short* EVt = (unsigned short*)alloc(1048576ULL * 2);  // [z][64][256]
  unsigned short* xd  = (unsigned short*)alloc(16777216ULL * 2); // bf16 working x
  unsigned short* xT  = (unsigned short*)alloc(16777216ULL * 2); // x^T; later Q/cat
  unsigned short* Qb4 = xT;   // alias: xT dead once pe is done; Q/cat [16384][1024]

  size_t rem = (ws_size > off) ? ws_size - off : 0;
  size_t Rbytes = rem > 512 ? rem - 512 : 0;
  if (Rbytes > 134217728ULL) Rbytes = 134217728ULL;
  int rowc = 16384;
  while (rowc > 256 && (size_t)rowc * 8192ULL > Rbytes) rowc >>= 1;
  if ((size_t)rowc * 8192ULL > Rbytes) {
    fill_canary_kernel<<<2048, 256, 0, stream>>>(xf, (long long)out_size);
    return;
  }
  char* R = alloc(Rbytes);

  auto cvt = [&](const float* s, unsigned short* d, float* df, long long n) {
    long long n4 = n / 4;
    int grid = (int)((n4 + 255) / 256);
    if (grid > 4096) grid = 4096;
    cvt_kernel<<<grid, 256, 0, stream>>>(s, d, df, n4);
  };

  cvt(x_in, xd, xf, 16777216);     // x: bf16 into ws, f32 master into d_out
  cvt(E_w, E16, nullptr, 1048576);

  for (int l = 0; l < 2; l++) {
    cvt(Wq + (size_t)l * 1048576, WqL, nullptr, 1048576);
    cvt(Wk + (size_t)l * 1048576, WkL, nullptr, 1048576);
    cvt(Wv + (size_t)l * 1048576, WvL, nullptr, 1048576);
    cvt(wo_w + (size_t)l * 1048576, WoL, nullptr, 1048576);
    cvt(ff_w1 + (size_t)l * 4194304, F1L, nullptr, 4194304);
    cvt(ff_w2 + (size_t)l * 4194304, F2L, nullptr, 4194304);

    // ---- xT[b][c][n] = x[b][n][c]
    transpose_kernel<<<dim3(64, 16, 4), 256, 0, stream>>>(xd, xT);

    // ---- xE[b][k][c] = sum_n E_w[k,n] * xT[b][c][n]   (pure NT, z = b)
    GemmP pe{};
    pe.A = E16; pe.sAm = 4096; pe.K = 4096;
    pe.B = xT; pe.sBn = 4096; pe.bLo = 4194304;
    pe.C = xE; pe.cLo = 262144; pe.sCm = 1024; pe.sCn = 1;
    pe.scale = 1.f; pe.cdtype = 0;
    gemm_nt<64,128,2,2><<<dim3(4, 8, 4), 256, 0, stream>>>(pe);

    // ---- EK[z][k][d] = xE[b] @ Wk[h]^T + E_b[k]   (z = b*16+h)
    GemmP pk{};
    pk.A = xE; pk.sAm = 1024; pk.K = 1024; pk.aHi = 262144; pk.aLo = 0;
    pk.B = WkL; pk.sBn = 1024; pk.bHi = 0; pk.bLo = 65536;
    pk.C = EK; pk.cHi = 262144; pk.cLo = 16384; pk.sCm = 64; pk.sCn = 1;
    pk.biasM = E_b; pk.scale = 1.f; pk.cdtype = 0;
    gemm_nt<64,64,2,2><<<dim3(4, 1, 64), 256, 0, stream>>>(pk);
    // ---- EVt[z][d][k] = (xE[b] @ Wv[h]^T + E_b[k])^T
    GemmP pv2 = pk;
    pv2.B = WvL; pv2.C = EVt; pv2.sCm = 1; pv2.sCn = 256;
    gemm_nt<64,64,2,2><<<dim3(4, 1, 64), 256, 0, stream>>>(pv2);

    // ---- Q (all batches) = x @ Wq^T : [16384,1024]   (overwrites xT region)
    GemmP pq{};
    pq.A = xd; pq.sAm = 1024; pq.K = 1024;
    pq.B = WqL; pq.sBn = 1024;
    pq.C = Qb4; pq.sCm = 1024; pq.sCn = 1;
    pq.scale = 1.f; pq.cdtype = 0;
    gemm256<<<dim3(64, 4, 1), 512, 0, stream>>>(pq);

    // ---- fused attention: cat[b][n][h*64+d] overwrites Q slice in place
    attn_kernel<<<dim3(32, 1, 64), 256, 0, stream>>>(Qb4, EK, EVt);

    // ---- xf += cat @ wo^T + wo_b   (f32 accumulate epilogue, all batches)
    GemmP pw{};
    pw.A = Qb4; pw.sAm = 1024; pw.K = 1024;
    pw.B = WoL; pw.sBn = 1024;
    pw.biasN = wo_b + (size_t)l * 1024;
    pw.C = xf; pw.cdtype = 3;
    pw.sCm = 1024; pw.sCn = 1; pw.scale = 1.f;
    gemm256<<<dim3(64, 4, 1), 512, 0, stream>>>(pw);

    add_ln_kernel<<<16384, 256, 0, stream>>>(xf, xd, ln1_g + (size_t)l * 1024,
                                             ln1_b + (size_t)l * 1024);

    // ---- FFN, row-chunked
    for (int r0 = 0; r0 < 16384; r0 += rowc) {
      GemmP f1{};
      f1.A = xd + (size_t)r0 * 1024; f1.sAm = 1024; f1.K = 1024;
      f1.B = F1L; f1.sBn = 1024;
      f1.C = R; f1.sCm = 4096; f1.sCn = 1;
      f1.biasN = ff_b1 + (size_t)l * 4096; f1.scale = 1.f; f1.relu = 1; f1.cdtype = 0;
      gemm256<<<dim3(rowc / 256, 16, 1), 512, 0, stream>>>(f1);

      GemmP f2{};
      f2.A = (unsigned short*)R; f2.sAm = 4096; f2.K = 4096;
      f2.B = F2L; f2.sBn = 4096;
      f2.biasN = ff_b2 + (size_t)l * 1024;
      f2.C = xf + (size_t)r0 * 1024; f2.cdtype = 3;
      f2.sCm = 1024; f2.sCn = 1; f2.scale = 1.f;
      gemm256<<<dim3(rowc / 256, 4, 1), 512, 0, stream>>>(f2);
    }
    // final LN of the net: bf16 copy not needed afterwards
    unsigned short* xdn = (l == 1) ? nullptr : xd;
    add_ln_kernel<<<16384, 256, 0, stream>>>(xf, xdn, ln2_g + (size_t)l * 1024,
                                             ln2_b + (size_t)l * 1024);
  }
}

// Round 11
// 1320.439 us; speedup vs baseline: 1.3249x; 1.1758x over previous
//
#include <hip/hip_runtime.h>
#include <hip/hip_bf16.h>

typedef __attribute__((ext_vector_type(8))) short short8;
typedef __attribute__((ext_vector_type(4))) float f32x4;

__device__ __forceinline__ unsigned short dev_f2bf(float f) {
  __hip_bfloat16 b = __float2bfloat16(f);
  union { __hip_bfloat16 b; unsigned short u; } c; c.b = b; return c.u;
}
__device__ __forceinline__ float dev_bf2f(unsigned short u) {
  union { unsigned int i; float f; } c; c.i = ((unsigned int)u) << 16; return c.f;
}

// async global->LDS, 16B per lane; dest = lds_base(wave-uniform) + lane*16
__device__ __forceinline__ void gload_lds16(const unsigned short* g, unsigned short* l) {
  __builtin_amdgcn_global_load_lds(
      (const __attribute__((address_space(1))) void*)(const void*)g,
      (__attribute__((address_space(3))) void*)(void*)l, 16, 0, 0);
}

struct GemmP {
  const unsigned short* A;   // bf16 bits
  const unsigned short* B;   // bf16 bits
  void* C;
  const float* biasN;        // bias by output col, may be null
  const float* biasM;        // bias by output row, may be null
  long long aHi, aLo, bHi, bLo, cHi, cLo;  // per-z base: (z>>4)*Hi + (z&15)*Lo
  int K;
  int sAm;                   // A row stride (k stride == 1)
  int sBn;                   // B row stride (k stride == 1)
  int sCm, sCn;
  float scale;
  int relu;
  int cdtype;                // 0=bf16, 1=f32, 3=f32 +=
};

// ---------------------------------------------------------------------------
// Big-GEMM: 256x256 tile, 512 threads (8 waves, 2Mx4N), BK=64, double-buffered
// LDS with counted vmcnt pipeline (never drains to 0 in main loop).
// LDS(row, c16) holds global(row, c16 ^ (row&7)); reads apply the same XOR.
// XCD swizzle (nwg%8==0): A-GROUPED decode: each XCD works a contiguous band
// of M with all N -> A panel L2-resident, minimizes FETCH.
// ---------------------------------------------------------------------------
__global__ __launch_bounds__(512, 2) void gemm256(GemmP p) {
  __shared__ __align__(16) unsigned short lds[2][2][256 * 64];  // 128 KiB

  const int tid = threadIdx.x;
  const int lane = tid & 63;
  const int wid = tid >> 6;       // 0..7
  const int wm = wid >> 2;        // 0..1
  const int wn = wid & 3;         // 0..3

  int id = blockIdx.y * gridDim.x + blockIdx.x;
  const int nwg = gridDim.x * gridDim.y;
  if ((nwg & 7) == 0) id = (id & 7) * (nwg >> 3) + (id >> 3);
  const long long m0 = (long long)(id / gridDim.y) * 256;   // A-grouped decode
  const long long n0 = (long long)(id % gridDim.y) * 256;

  const int srow8 = lane >> 3;                 // 0..7
  const int scol = ((lane & 7) ^ srow8) * 8;   // swizzled short offset

  f32x4 acc[8][4];
#pragma unroll
  for (int i = 0; i < 8; i++)
#pragma unroll
    for (int j = 0; j < 4; j++)
      acc[i][j] = f32x4{0.f, 0.f, 0.f, 0.f};

  const int nt = p.K >> 6;

  auto stage = [&](int buf, int t) {
    const long long k0 = (long long)t * 64;
#pragma unroll
    for (int h = 0; h < 4; h++)
      gload_lds16(p.A + (m0 + h * 64 + wid * 8 + srow8) * p.sAm + k0 + scol,
                  &lds[buf][0][(h * 64 + wid * 8) * 64]);
#pragma unroll
    for (int h = 0; h < 4; h++)
      gload_lds16(p.B + (n0 + h * 64 + wid * 8 + srow8) * p.sBn + k0 + scol,
                  &lds[buf][1][(h * 64 + wid * 8) * 64]);
  };

  stage(0, 0);
  stage(1, 1);

  for (int t = 0; t < nt; t++) {
    const int cur = t & 1;
    if (t + 1 < nt) asm volatile("s_waitcnt vmcnt(8)" ::: "memory");
    else            asm volatile("s_waitcnt vmcnt(0)" ::: "memory");
    __builtin_amdgcn_s_barrier();
    __builtin_amdgcn_sched_barrier(0);

    const unsigned short* Asb = lds[cur][0];
    const unsigned short* Bsb = lds[cur][1];
#pragma unroll
    for (int ks = 0; ks < 2; ks++) {
      const int c16 = ks * 4 + (lane >> 4);
      short8 a[8], b[4];
#pragma unroll
      for (int i = 0; i < 8; i++) {
        const int r = wm * 128 + i * 16 + (lane & 15);
        a[i] = *(const short8*)&Asb[r * 64 + ((c16 ^ (r & 7)) << 3)];
      }
#pragma unroll
      for (int j = 0; j < 4; j++) {
        const int r = wn * 64 + j * 16 + (lane & 15);
        b[j] = *(const short8*)&Bsb[r * 64 + ((c16 ^ (r & 7)) << 3)];
      }
      __builtin_amdgcn_s_setprio(1);
#pragma unroll
      for (int i = 0; i < 8; i++)
#pragma unroll
        for (int j = 0; j < 4; j++)
          acc[i][j] = __builtin_amdgcn_mfma_f32_16x16x32_bf16(a[i], b[j], acc[i][j], 0, 0, 0);
      __builtin_amdgcn_s_setprio(0);
    }
    __builtin_amdgcn_sched_barrier(0);
    __builtin_amdgcn_s_barrier();
    __builtin_amdgcn_sched_barrier(0);
    if (t + 2 < nt) stage(cur, t + 2);
  }

#pragma unroll
  for (int i = 0; i < 8; i++) {
#pragma unroll
    for (int j = 0; j < 4; j++) {
      const int col = (int)n0 + wn * 64 + j * 16 + (lane & 15);
      float bn = p.biasN ? p.biasN[col] : 0.f;
#pragma unroll
      for (int r = 0; r < 4; r++) {
        const long long row = m0 + wm * 128 + i * 16 + ((lane >> 4) << 2) + r;
        float v = acc[i][j][r] * p.scale + bn;
        if (p.relu) v = fmaxf(v, 0.f);
        const long long addr = row * p.sCm + col;
        if (p.cdtype == 0)      ((unsigned short*)p.C)[addr] = dev_f2bf(v);
        else if (p.cdtype == 3) ((float*)p.C)[addr] += v;
        else                    ((float*)p.C)[addr] = v;
      }
    }
  }
}

// ---------------------------------------------------------------------------
// Fully fused attention, QBLK=64: per block = 64 q-rows x one head z.
// LDS: u0 = [As 8KB | Bs 32KB] (Ps 32KB aliases u0 after phase 1), Vs 32KB.
// Total 73 KB -> 2 blocks/CU. Phases: QK^T -> in-reg softmax -> Ps(bf16,
// granule-XOR) -> PV -> bf16 store in place over the Q slice.
// ---------------------------------------------------------------------------
__global__ __launch_bounds__(256, 2) void attn_kernel(
    const unsigned short* __restrict__ Q, const unsigned short* __restrict__ EK,
    const unsigned short* __restrict__ EVt) {
  __shared__ __align__(16) unsigned short u0[20480];       // As(4096) + Bs(16384)
  __shared__ __align__(16) unsigned short Vs[64 * 256];    // 32 KB
  __shared__ float red[2][2][64];

  unsigned short* As = u0;           // 64 x 64
  unsigned short* Bs = u0 + 4096;    // 256 x 64
  unsigned short* Ps = u0;           // 64 x 256 (aliases As+Bs after QK phase)

  const int tid = threadIdx.x;
  const int lane = tid & 63;
  const int wid = tid >> 6;
  const int wm = wid >> 1, wn = wid & 1;   // 2x2 wave grid
  const int m0 = blockIdx.x * 64;
  const int z = blockIdx.z;
  unsigned short* Qz = (unsigned short*)Q + (long long)(z >> 4) * 4194304 + (long long)(z & 15) * 64;
  const unsigned short* EKz = EK + (long long)z * 16384;
  const unsigned short* EVz = EVt + (long long)z * 16384;

  const int srow = tid >> 3;
  const int scol = ((tid & 7) ^ (srow & 7)) * 8;

#pragma unroll
  for (int i = 0; i < 2; i++)
    gload_lds16(Qz + (long long)(m0 + i * 32 + srow) * 1024 + scol, &As[i * 2048 + wid * 512]);
#pragma unroll
  for (int i = 0; i < 8; i++)
    gload_lds16(EKz + (long long)(i * 32 + srow) * 64 + scol, &Bs[i * 2048 + wid * 512]);
  // EVt: physical granule pg holds logical granule (pg&31)^(d&7) of row d=pg>>5
#pragma unroll
  for (int c = 0; c < 8; c++) {
    const int pg = (c * 4 + wid) * 64 + lane;
    const int d = pg >> 5, gp = pg & 31;
    gload_lds16(EVz + d * 256 + ((gp ^ (d & 7)) << 3), &Vs[(c * 4 + wid) * 512]);
  }
  __syncthreads();

  f32x4 acc[2][8];
#pragma unroll
  for (int i = 0; i < 2; i++)
#pragma unroll
    for (int j = 0; j < 8; j++)
      acc[i][j] = f32x4{0.f, 0.f, 0.f, 0.f};

#pragma unroll
  for (int ks = 0; ks < 2; ks++) {
    const int c16 = ks * 4 + (lane >> 4);
    short8 a[2], b[8];
#pragma unroll
    for (int i = 0; i < 2; i++) {
      const int row = wm * 32 + i * 16 + (lane & 15);
      a[i] = *(const short8*)&As[row * 64 + ((c16 ^ (row & 7)) << 3)];
    }
#pragma unroll
    for (int j = 0; j < 8; j++) {
      const int row = wn * 128 + j * 16 + (lane & 15);
      b[j] = *(const short8*)&Bs[row * 64 + ((c16 ^ (row & 7)) << 3)];
    }
#pragma unroll
    for (int i = 0; i < 2; i++)
#pragma unroll
      for (int j = 0; j < 8; j++)
        acc[i][j] = __builtin_amdgcn_mfma_f32_16x16x32_bf16(a[i], b[j], acc[i][j], 0, 0, 0);
  }

  const int rr4 = (lane >> 4) << 2;
#pragma unroll
  for (int i = 0; i < 2; i++) {
#pragma unroll
    for (int r = 0; r < 4; r++) {
      float m = acc[i][0][r];
#pragma unroll
      for (int j = 1; j < 8; j++) m = fmaxf(m, acc[i][j][r]);
      m = fmaxf(m, __shfl_xor(m, 1));
      m = fmaxf(m, __shfl_xor(m, 2));
      m = fmaxf(m, __shfl_xor(m, 4));
      m = fmaxf(m, __shfl_xor(m, 8));
      if ((lane & 15) == 0) red[0][wn][wm * 32 + i * 16 + rr4 + r] = m;
    }
  }
  __syncthreads();
  float fm[2][4];
#pragma unroll
  for (int i = 0; i < 2; i++)
#pragma unroll
    for (int r = 0; r < 4; r++) {
      const int row = wm * 32 + i * 16 + rr4 + r;
      fm[i][r] = fmaxf(red[0][0][row], red[0][1][row]);
    }
#pragma unroll
  for (int i = 0; i < 2; i++) {
#pragma unroll
    for (int r = 0; r < 4; r++) {
      float s = 0.f;
#pragma unroll
      for (int j = 0; j < 8; j++) {
        float e = __expf((acc[i][j][r] - fm[i][r]) * 0.125f);
        acc[i][j][r] = e;
        s += e;
      }
      s += __shfl_xor(s, 1);
      s += __shfl_xor(s, 2);
      s += __shfl_xor(s, 4);
      s += __shfl_xor(s, 8);
      if ((lane & 15) == 0) red[1][wn][wm * 32 + i * 16 + rr4 + r] = s;
    }
  }
  __syncthreads();   // last As/Bs reads done; Ps may now overwrite u0
#pragma unroll
  for (int i = 0; i < 2; i++) {
#pragma unroll
    for (int r = 0; r < 4; r++) {
      const int row = wm * 32 + i * 16 + rr4 + r;
      const float inv = 1.f / (red[1][0][row] + red[1][1][row]);
#pragma unroll
      for (int j = 0; j < 8; j++) {
        const int col = wn * 128 + j * 16 + (lane & 15);
        Ps[row * 256 + (((col >> 3) ^ (row & 7)) << 3) + (col & 7)] =
            dev_f2bf(acc[i][j][r] * inv);
      }
    }
  }
  __syncthreads();

  // PV: out[q][d] = sum_k P[q,k] * EVt[d,k]; per wave 32q x 32d
  f32x4 acc2[2][2];
#pragma unroll
  for (int i = 0; i < 2; i++)
#pragma unroll
    for (int jj = 0; jj < 2; jj++)
      acc2[i][jj] = f32x4{0.f, 0.f, 0.f, 0.f};

#pragma unroll
  for (int ks = 0; ks < 8; ks++) {
    const int G = ks * 4 + (lane >> 4);
    short8 pa[2], pb[2];
#pragma unroll
    for (int i = 0; i < 2; i++) {
      const int row = wm * 32 + i * 16 + (lane & 15);
      pa[i] = *(const short8*)&Ps[row * 256 + ((G ^ (row & 7)) << 3)];
    }
#pragma unroll
    for (int jj = 0; jj < 2; jj++) {
      const int d = wn * 32 + jj * 16 + (lane & 15);
      pb[jj] = *(const short8*)&Vs[d * 256 + ((G ^ (d & 7)) << 3)];
    }
#pragma unroll
    for (int i = 0; i < 2; i++)
#pragma unroll
      for (int jj = 0; jj < 2; jj++)
        acc2[i][jj] = __builtin_amdgcn_mfma_f32_16x16x32_bf16(pa[i], pb[jj], acc2[i][jj], 0, 0, 0);
  }

#pragma unroll
  for (int i = 0; i < 2; i++) {
#pragma unroll
    for (int jj = 0; jj < 2; jj++) {
#pragma unroll
      for (int r = 0; r < 4; r++) {
        const int qrow = m0 + wm * 32 + i * 16 + rr4 + r;
        const int dcol = wn * 32 + jj * 16 + (lane & 15);
        Qz[(long long)qrow * 1024 + dcol] = dev_f2bf(acc2[i][jj][r]);
      }
    }
  }
}

// General NT GEMM (small/batched shapes): C[z,m,n] = scale*sum_k A[m,k]*B[n,k]
template<int BM, int BN, int WM, int WN>
__global__ __launch_bounds__(256, 2) void gemm_nt(GemmP p) {
  constexpr int BK = 64;
  constexpr int TM = BM / WM, TN = BN / WN;
  constexpr int FM = TM / 16, FN = TN / 16;
  __shared__ __align__(16) unsigned short As[BM * BK];
  __shared__ __align__(16) unsigned short Bs[BN * BK];

  const int tid = threadIdx.x;
  const int lane = tid & 63;
  const int wid = tid >> 6;
  const int wm = wid / WN, wn = wid % WN;
  const int m0 = blockIdx.x * BM;
  const int n0 = blockIdx.y * BN;
  const int z = blockIdx.z;
  const int zq = z >> 4, zr = z & 15;
  const unsigned short* Ag = p.A + (long long)zq * p.aHi + (long long)zr * p.aLo;
  const unsigned short* Bg = p.B + (long long)zq * p.bHi + (long long)zr * p.bLo;

  const int srow = tid >> 3;                      // 0..31
  const int scol = ((tid & 7) ^ (srow & 7)) * 8;  // swizzled 16B column
  constexpr int AC = BM / 32, BC = BN / 32;

  f32x4 acc[FM][FN];
#pragma unroll
  for (int i = 0; i < FM; i++)
#pragma unroll
    for (int j = 0; j < FN; j++)
      acc[i][j] = f32x4{0.f, 0.f, 0.f, 0.f};

  for (int k0 = 0; k0 < p.K; k0 += BK) {
#pragma unroll
    for (int i = 0; i < AC; i++)
      gload_lds16(Ag + (long long)(m0 + i * 32 + srow) * p.sAm + (k0 + scol),
                  &As[i * 2048 + wid * 512]);
#pragma unroll
    for (int i = 0; i < BC; i++)
      gload_lds16(Bg + (long long)(n0 + i * 32 + srow) * p.sBn + (k0 + scol),
                  &Bs[i * 2048 + wid * 512]);
    __syncthreads();
#pragma unroll
    for (int ks = 0; ks < 2; ks++) {
      const int c16 = ks * 4 + (lane >> 4);
      short8 a[FM], b[FN];
#pragma unroll
      for (int i = 0; i < FM; i++) {
        const int row = wm * TM + i * 16 + (lane & 15);
        a[i] = *(const short8*)&As[row * 64 + ((c16 ^ (row & 7)) << 3)];
      }
#pragma unroll
      for (int j = 0; j < FN; j++) {
        const int row = wn * TN + j * 16 + (lane & 15);
        b[j] = *(const short8*)&Bs[row * 64 + ((c16 ^ (row & 7)) << 3)];
      }
#pragma unroll
      for (int i = 0; i < FM; i++)
#pragma unroll
        for (int j = 0; j < FN; j++)
          acc[i][j] = __builtin_amdgcn_mfma_f32_16x16x32_bf16(a[i], b[j], acc[i][j], 0, 0, 0);
    }
    __syncthreads();
  }

  const long long zc_ = (long long)zq * p.cHi + (long long)zr * p.cLo;
#pragma unroll
  for (int i = 0; i < FM; i++) {
#pragma unroll
    for (int j = 0; j < FN; j++) {
      const int col = n0 + wn * TN + j * 16 + (lane & 15);
      float bn = p.biasN ? p.biasN[col] : 0.f;
#pragma unroll
      for (int r = 0; r < 4; r++) {
        const int row = m0 + wm * TM + i * 16 + ((lane >> 4) << 2) + r;
        float v = acc[i][j][r] * p.scale + bn;
        if (p.biasM) v += p.biasM[row];
        if (p.relu) v = fmaxf(v, 0.f);
        const long long addr = zc_ + (long long)row * p.sCm + (long long)col * p.sCn;
        if (p.cdtype == 0)      ((unsigned short*)p.C)[addr] = dev_f2bf(v);
        else if (p.cdtype == 3) ((float*)p.C)[addr] += v;
        else                    ((float*)p.C)[addr] = v;
      }
    }
  }
}

// 64x64 tiled transpose: in [b][4096][1024] -> out [b][1024][4096] (bf16)
__global__ __launch_bounds__(256) void transpose_kernel(const unsigned short* __restrict__ in,
                                                        unsigned short* __restrict__ out) {
  __shared__ unsigned short t[64][72];
  const int b = blockIdx.z;
  const int n0 = blockIdx.x * 64, c0 = blockIdx.y * 64;
  const int r = threadIdx.x >> 2;          // 0..63
  const int cc = (threadIdx.x & 3) * 16;   // 0,16,32,48
  const unsigned short* ip = in + (size_t)b * 4194304 + (size_t)n0 * 1024 + c0;
  *(short8*)&t[r][cc]     = *(const short8*)(ip + (size_t)r * 1024 + cc);
  *(short8*)&t[r][cc + 8] = *(const short8*)(ip + (size_t)r * 1024 + cc + 8);
  __syncthreads();
  unsigned short* op = out + (size_t)b * 4194304 + (size_t)c0 * 4096 + n0;
  short8 w0, w1;
#pragma unroll
  for (int j = 0; j < 8; j++) {
    w0[j] = (short)t[cc + j][r];
    w1[j] = (short)t[cc + 8 + j][r];
  }
  *(short8*)(op + (size_t)r * 4096 + cc)     = w0;
  *(short8*)(op + (size_t)r * 4096 + cc + 8) = w1;
}

// f32 -> bf16 (optionally also copy raw f32), x4 vectorized, grid-stride
__global__ void cvt_kernel(const float* __restrict__ src, unsigned short* __restrict__ dst,
                           float* __restrict__ dstf, long long n4) {
  long long i = (long long)blockIdx.x * blockDim.x + threadIdx.x;
  const long long stride = (long long)gridDim.x * blockDim.x;
  for (; i < n4; i += stride) {
    float4 v = ((const float4*)src)[i];
    ushort4 u;
    u.x = dev_f2bf(v.x); u.y = dev_f2bf(v.y); u.z = dev_f2bf(v.z); u.w = dev_f2bf(v.w);
    ((ushort4*)dst)[i] = u;
    if (dstf) ((float4*)dstf)[i] = v;
  }
}

// LN over rows of 1024: t = xf + bf16dec(xd)  (xd holds y as bf16).
// Writes LN result to xf, and bf16 copy to xd if wx.
__global__ __launch_bounds__(256) void add_ln_kernel(float* __restrict__ xf,
    unsigned short* __restrict__ xd,
    const float* __restrict__ g, const float* __restrict__ b, int wx) {
  const long long row = blockIdx.x;
  const int tid = threadIdx.x;
  float4 t = ((const float4*)(xf + row * 1024))[tid];
  ushort4 yv = ((const ushort4*)(xd + row * 1024))[tid];
  t.x += dev_bf2f(yv.x); t.y += dev_bf2f(yv.y);
  t.z += dev_bf2f(yv.z); t.w += dev_bf2f(yv.w);
  float s = t.x + t.y + t.z + t.w;
  float ss = t.x * t.x + t.y * t.y + t.z * t.z + t.w * t.w;
#pragma unroll
  for (int off = 32; off > 0; off >>= 1) { s += __shfl_xor(s, off); ss += __shfl_xor(ss, off); }
  __shared__ float sm[8];
  const int wid = tid >> 6, lane = tid & 63;
  if (lane == 0) { sm[wid] = s; sm[4 + wid] = ss; }
  __syncthreads();
  s = sm[0] + sm[1] + sm[2] + sm[3];
  ss = sm[4] + sm[5] + sm[6] + sm[7];
  const float mean = s * (1.f / 1024.f);
  const float var = ss * (1.f / 1024.f) - mean * mean;
  const float rs = rsqrtf(var + 1e-5f);
  float4 gv = ((const float4*)g)[tid];
  float4 bv = ((const float4*)b)[tid];
  float4 o = {(t.x - mean) * rs * gv.x + bv.x, (t.y - mean) * rs * gv.y + bv.y,
              (t.z - mean) * rs * gv.z + bv.z, (t.w - mean) * rs * gv.w + bv.w};
  ((float4*)(xf + row * 1024))[tid] = o;
  if (wx) {
    ushort4 ob;
    ob.x = dev_f2bf(o.x); ob.y = dev_f2bf(o.y); ob.z = dev_f2bf(o.z); ob.w = dev_f2bf(o.w);
    ((ushort4*)(xd + row * 1024))[tid] = ob;
  }
}

// canary: unambiguous "workspace too small" signal (absmax ~ 100+max|ref|)
__global__ void fill_canary_kernel(float* p, long long n) {
  long long i = (long long)blockIdx.x * blockDim.x + threadIdx.x;
  const long long stride = (long long)gridDim.x * blockDim.x;
  for (; i < n; i += stride) p[i] = 100.0f;
}

extern "C" void kernel_launch(void* const* d_in, const int* in_sizes, int n_in,
                              void* d_out, int out_size, void* d_ws, size_t ws_size,
                              hipStream_t stream) {
  const float* x_in  = (const float*)d_in[0];
  const float* E_w   = (const float*)d_in[1];
  const float* E_b   = (const float*)d_in[2];
  const float* Wq    = (const float*)d_in[3];
  const float* Wk    = (const float*)d_in[4];
  const float* Wv    = (const float*)d_in[5];
  const float* wo_w  = (const float*)d_in[6];
  const float* wo_b  = (const float*)d_in[7];
  const float* ln1_g = (const float*)d_in[8];
  const float* ln1_b = (const float*)d_in[9];
  const float* ff_w1 = (const float*)d_in[10];
  const float* ff_b1 = (const float*)d_in[11];
  const float* ff_w2 = (const float*)d_in[12];
  const float* ff_b2 = (const float*)d_in[13];
  const float* ln2_g = (const float*)d_in[14];
  const float* ln2_b = (const float*)d_in[15];

  float* xf = (float*)d_out;   // f32 residual master lives in d_out

  char* ws = (char*)d_ws;
  size_t off = 0;
  auto alloc = [&](size_t bytes) -> char* {
    char* p = ws + off;
    off = (off + bytes + 255) & ~(size_t)255;
    return p;
  };
  unsigned short* E16 = (unsigned short*)alloc(1048576ULL * 2);  // E_w bf16 [256,4096]
  unsigned short* WqL = (unsigned short*)alloc(1048576ULL * 2);  // per-layer slices
  unsigned short* WkL = (unsigned short*)alloc(1048576ULL * 2);
  unsigned short* WvL = (unsigned short*)alloc(1048576ULL * 2);
  unsigned short* WoL = (unsigned short*)alloc(1048576ULL * 2);
  unsigned short* F1L = (unsigned short*)alloc(4194304ULL * 2);
  unsigned short* F2L = (unsigned short*)alloc(4194304ULL * 2);
  unsigned short* xE  = (unsigned short*)alloc(1048576ULL * 2);  // [b][256][1024]
  unsigned short* EK  = (unsigned short*)alloc(1048576ULL * 2);  // [z][256][64]
  unsigned short* EVt = (unsigned short*)alloc(1048576ULL * 2);  // [z][64][256]
  unsigned short* xd  = (unsigned short*)alloc(16777216ULL * 2); // bf16 working x / y
  unsigned short* xT  = (unsigned short*)alloc(16777216ULL * 2); // x^T; later Q/cat
  unsigned short* Qb4 = xT;   // alias: xT dead once pe is done; Q/cat [16384][1024]

  size_t rem = (ws_size > off) ? ws_size - off : 0;
  size_t Rbytes = rem > 512 ? rem - 512 : 0;
  if (Rbytes > 134217728ULL) Rbytes = 134217728ULL;
  int rowc = 16384;
  while (rowc > 256 && (size_t)rowc * 8192ULL > Rbytes) rowc >>= 1;
  if ((size_t)rowc * 8192ULL > Rbytes) {
    fill_canary_kernel<<<2048, 256, 0, stream>>>(xf, (long long)out_size);
    return;
  }
  char* R = alloc(Rbytes);

  auto cvt = [&](const float* s, unsigned short* d, float* df, long long n) {
    long long n4 = n / 4;
    int grid = (int)((n4 + 255) / 256);
    if (grid > 4096) grid = 4096;
    cvt_kernel<<<grid, 256, 0, stream>>>(s, d, df, n4);
  };

  cvt(x_in, xd, xf, 16777216);     // x: bf16 into ws, f32 master into d_out
  cvt(E_w, E16, nullptr, 1048576);

  for (int l = 0; l < 2; l++) {
    cvt(Wq + (size_t)l * 1048576, WqL, nullptr, 1048576);
    cvt(Wk + (size_t)l * 1048576, WkL, nullptr, 1048576);
    cvt(Wv + (size_t)l * 1048576, WvL, nullptr, 1048576);
    cvt(wo_w + (size_t)l * 1048576, WoL, nullptr, 1048576);
    cvt(ff_w1 + (size_t)l * 4194304, F1L, nullptr, 4194304);
    cvt(ff_w2 + (size_t)l * 4194304, F2L, nullptr, 4194304);

    // ---- xT[b][c][n] = x[b][n][c]
    transpose_kernel<<<dim3(64, 16, 4), 256, 0, stream>>>(xd, xT);

    // ---- xE[b][k][c] = sum_n E_w[k,n] * xT[b][c][n]   (pure NT, z = b)
    GemmP pe{};
    pe.A = E16; pe.sAm = 4096; pe.K = 4096;
    pe.B = xT; pe.sBn = 4096; pe.bLo = 4194304;
    pe.C = xE; pe.cLo = 262144; pe.sCm = 1024; pe.sCn = 1;
    pe.scale = 1.f; pe.cdtype = 0;
    gemm_nt<64,64,2,2><<<dim3(4, 16, 4), 256, 0, stream>>>(pe);

    // ---- EK[z][k][d] = xE[b] @ Wk[h]^T + E_b[k]   (z = b*16+h)
    GemmP pk{};
    pk.A = xE; pk.sAm = 1024; pk.K = 1024; pk.aHi = 262144; pk.aLo = 0;
    pk.B = WkL; pk.sBn = 1024; pk.bHi = 0; pk.bLo = 65536;
    pk.C = EK; pk.cHi = 262144; pk.cLo = 16384; pk.sCm = 64; pk.sCn = 1;
    pk.biasM = E_b; pk.scale = 1.f; pk.cdtype = 0;
    gemm_nt<64,64,2,2><<<dim3(4, 1, 64), 256, 0, stream>>>(pk);
    // ---- EVt[z][d][k] = (xE[b] @ Wv[h]^T + E_b[k])^T
    GemmP pv2 = pk;
    pv2.B = WvL; pv2.C = EVt; pv2.sCm = 1; pv2.sCn = 256;
    gemm_nt<64,64,2,2><<<dim3(4, 1, 64), 256, 0, stream>>>(pv2);

    // ---- Q (all batches) = x @ Wq^T : [16384,1024]   (overwrites xT region)
    GemmP pq{};
    pq.A = xd; pq.sAm = 1024; pq.K = 1024;
    pq.B = WqL; pq.sBn = 1024;
    pq.C = Qb4; pq.sCm = 1024; pq.sCn = 1;
    pq.scale = 1.f; pq.cdtype = 0;
    gemm256<<<dim3(64, 4, 1), 512, 0, stream>>>(pq);

    // ---- fused attention: cat[b][n][h*64+d] overwrites Q slice in place
    attn_kernel<<<dim3(64, 1, 64), 256, 0, stream>>>(Qb4, EK, EVt);

    // ---- y = cat @ wo^T + wo_b -> bf16 into xd (old x bf16 is dead)
    GemmP pw{};
    pw.A = Qb4; pw.sAm = 1024; pw.K = 1024;
    pw.B = WoL; pw.sBn = 1024;
    pw.biasN = wo_b + (size_t)l * 1024;
    pw.C = xd; pw.cdtype = 0;
    pw.sCm = 1024; pw.sCn = 1; pw.scale = 1.f;
    gemm256<<<dim3(64, 4, 1), 512, 0, stream>>>(pw);

    // ---- x = LN1(xf + y)
    add_ln_kernel<<<16384, 256, 0, stream>>>(xf, xd, ln1_g + (size_t)l * 1024,
                                             ln1_b + (size_t)l * 1024, 1);

    // ---- FFN, row-chunked: h = relu(x@W1^T+b1); y = h@W2^T+b2 -> xd rows
    for (int r0 = 0; r0 < 16384; r0 += rowc) {
      GemmP f1{};
      f1.A = xd + (size_t)r0 * 1024; f1.sAm = 1024; f1.K = 1024;
      f1.B = F1L; f1.sBn = 1024;
      f1.C = R; f1.sCm = 4096; f1.sCn = 1;
      f1.biasN = ff_b1 + (size_t)l * 4096; f1.scale = 1.f; f1.relu = 1; f1.cdtype = 0;
      gemm256<<<dim3(rowc / 256, 16, 1), 512, 0, stream>>>(f1);

      GemmP f2{};
      f2.A = (unsigned short*)R; f2.sAm = 4096; f2.K = 4096;
      f2.B = F2L; f2.sBn = 4096;
      f2.biasN = ff_b2 + (size_t)l * 1024;
      f2.C = xd + (size_t)r0 * 1024; f2.cdtype = 0;
      f2.sCm = 1024; f2.sCn = 1; f2.scale = 1.f;
      gemm256<<<dim3(rowc / 256, 4, 1), 512, 0, stream>>>(f2);
    }
    // ---- x = LN2(xf + y); final layer skips the bf16 copy
    add_ln_kernel<<<16384, 256, 0, stream>>>(xf, xd, ln2_g + (size_t)l * 1024,
                                             ln2_b + (size_t)l * 1024, (l == 1) ? 0 : 1);
  }
}